// Round 4
// baseline (12453.503 us; speedup 1.0000x reference)
//
#include <hip/hip_runtime.h>

// ---------------------------------------------------------------------------
// <psi|U^dag O U|psi>, NQ=8, r=64 d=16 rl=16 ro=4.
// R4: whole middle chain (G1..G5, sites 1..6) on bf16x3 MFMA. All
// intermediates (incl. env) are split-planes: u32 = bf16(hi) | bf16(lo)<<16,
// layout [k/32][n][k%32]. One templated MFMA kernel, A-operands pre-packed in
// fragment order. Boundary sites 0/7 stay fp32 (cheap rank-structured chains);
// s7 w-build + dot fused into one LDS-staged kernel (was 300 us latency-bound).
//
// Plane n-layouts (per A-chunk a4 = A-A0, chunk width 16):
//  envP  k=a(64)       n=(l,o,m2,b)   = l*4096+o*1024+m2*64+b      Nfull 65536
//  t1    k=(l,i)(256)  n=(o,m2,b,a4)  = o*16384+m2*1024+b*16+a4    Nfull 65536
//  t2    k=(o,j)(64)   n=(L,m2,b,a4)  = L*16384+m2*1024+b*16+a4    Nfull 262144
//  t3    k=(m2,k2)(256) n=(O2,b,L,a4) = O2*16384+b*256+L*16+a4     Nfull 65536
//  t4    k=(b,s)(1024) n=(M2,L,O2,a4) = M2*1024+L*64+O2*16+a4      Nfull 16384
// ---------------------------------------------------------------------------

typedef __attribute__((ext_vector_type(8))) short bf16x8;
typedef __attribute__((ext_vector_type(4))) float f32x4;
typedef __attribute__((ext_vector_type(4))) unsigned short us4;

static __device__ __forceinline__ unsigned short f2bf(float x) {
    union { float f; unsigned u; } a; a.f = x;
    return (unsigned short)((a.u + 0x7FFF + ((a.u >> 16) & 1)) >> 16);
}
static __device__ __forceinline__ float bf2f(unsigned short h) {
    union { unsigned u; float f; } a; a.u = (unsigned)h << 16; return a.f;
}
static __device__ __forceinline__ unsigned split2(float x) {
    unsigned short h = f2bf(x);
    unsigned short l = f2bf(x - bf2f(h));
    return (unsigned)h | ((unsigned)l << 16);
}

__global__ void write_diag_kernel(float* out, float v) {
    if (threadIdx.x == 0 && blockIdx.x == 0) out[0] = v;
}
__global__ void zero_out(float* o) {
    if (threadIdx.x == 0 && blockIdx.x == 0) o[0] = 0.0f;
}

// ---- A-operand fragment packs -------------------------------------------
// Pack layout: [(k0*MT + mt)*2 + hl][lane][8];  frag k = k0*32+quad*8+j,
// m = mt*16 + (lane&15).

// G2 (Ud) / G4 (U), MT=16, K=256
__global__ void prep_apack(const float* __restrict__ layer,
                           unsigned short* __restrict__ Ap2,
                           unsigned short* __restrict__ Ap4) {
    int idx = blockIdx.x * 256 + threadIdx.x;   // 65536
    int q = idx >> 13, k0 = (idx >> 10) & 7, mt = (idx >> 6) & 15, lane = idx & 63;
    int quad = lane >> 4, r = lane & 15;
    unsigned short h2[8], l2[8], h4[8], l4[8];
#pragma unroll
    for (int j = 0; j < 8; j++) {
        int k = k0 * 32 + quad * 8 + j;
        int m = mt * 16 + r;
        float v2 = layer[(size_t)q * 65536 +
                         (size_t)((((k >> 4) * 16 + (m >> 4)) * 16 + (k & 15)) * 16 + (m & 15))];
        float v4 = layer[(size_t)q * 65536 +
                         (size_t)((((k >> 4) * 16 + (k & 15)) * 16 + (m >> 4)) * 16 + (m & 15))];
        h2[j] = f2bf(v2); l2[j] = f2bf(v2 - bf2f(h2[j]));
        h4[j] = f2bf(v4); l4[j] = f2bf(v4 - bf2f(h4[j]));
    }
    size_t base = ((size_t)((q * 8 + k0) * 16 + mt) * 2) * 512 + lane * 8;
    *(us4*)(Ap2 + base)       = *(us4*)&h2[0];
    *(us4*)(Ap2 + base + 4)   = *(us4*)&h2[4];
    *(us4*)(Ap2 + base + 512) = *(us4*)&l2[0];
    *(us4*)(Ap2 + base + 516) = *(us4*)&l2[4];
    *(us4*)(Ap4 + base)       = *(us4*)&h4[0];
    *(us4*)(Ap4 + base + 4)   = *(us4*)&h4[4];
    *(us4*)(Ap4 + base + 512) = *(us4*)&l4[0];
    *(us4*)(Ap4 + base + 516) = *(us4*)&l4[4];
}

// G1 (S as A): Amat[k=a][m=(i,a4)] = state[q][a][i][A0+a4], per (q,chunk c)
__global__ void prep_spack1(const float* __restrict__ state,
                            unsigned short* __restrict__ Sp1) {
    int idx = blockIdx.x * 256 + threadIdx.x;   // 65536
    int q = idx >> 13, c = (idx >> 11) & 3, k0 = (idx >> 10) & 1,
        mt = (idx >> 6) & 15, lane = idx & 63;
    int quad = lane >> 4, lr = lane & 15;
    unsigned short h[8], l[8];
#pragma unroll
    for (int j = 0; j < 8; j++) {
        int k = k0 * 32 + quad * 8 + j;
        float v = state[(size_t)q * 65536 + (size_t)(k * 16 + mt) * 64 + c * 16 + lr];
        h[j] = f2bf(v); l[j] = f2bf(v - bf2f(h[j]));
    }
    size_t base = (size_t)(q * 4 + c) * 32768 + ((size_t)(k0 * 16 + mt) * 2) * 512 + lane * 8;
    *(us4*)(Sp1 + base)       = *(us4*)&h[0];
    *(us4*)(Sp1 + base + 4)   = *(us4*)&h[4];
    *(us4*)(Sp1 + base + 512) = *(us4*)&l[0];
    *(us4*)(Sp1 + base + 516) = *(us4*)&l[4];
}

// G5 (S as A): Amat[k=(b,s)][m=B'] = state[q][b][s][B'], MT=4, K=1024
__global__ void prep_spack5(const float* __restrict__ state,
                            unsigned short* __restrict__ Sp5) {
    int idx = blockIdx.x * 256 + threadIdx.x;   // 65536
    int q = idx >> 13, k0 = (idx >> 8) & 31, mt = (idx >> 6) & 3, lane = idx & 63;
    int quad = lane >> 4, lr = lane & 15;
    unsigned short h[8], l[8];
#pragma unroll
    for (int j = 0; j < 8; j++) {
        int k = k0 * 32 + quad * 8 + j;
        float v = state[(size_t)q * 65536 + (size_t)k * 64 + mt * 16 + lr];
        h[j] = f2bf(v); l[j] = f2bf(v - bf2f(h[j]));
    }
    size_t base = (size_t)q * 131072 + ((size_t)(k0 * 4 + mt) * 2) * 512 + lane * 8;
    *(us4*)(Sp5 + base)       = *(us4*)&h[0];
    *(us4*)(Sp5 + base + 4)   = *(us4*)&h[4];
    *(us4*)(Sp5 + base + 512) = *(us4*)&l[0];
    *(us4*)(Sp5 + base + 516) = *(us4*)&l[4];
}

// G3 (O as A): Amat[k=(o,j2)][m=(k2,O2)] = oper[q][o][j2][k2][O2], MT=4, K=64
__global__ void prep_opack3(const float* __restrict__ oper,
                            unsigned short* __restrict__ Op3) {
    int idx = blockIdx.x * 256 + threadIdx.x;   // 4096
    int q = idx >> 9, k0 = (idx >> 8) & 1, mt = (idx >> 6) & 3, lane = idx & 63;
    int quad = lane >> 4, lr = lane & 15;
    unsigned short h[8], l[8];
#pragma unroll
    for (int j = 0; j < 8; j++) {
        int k = k0 * 32 + quad * 8 + j;
        int m = mt * 16 + lr;
        float v = oper[(size_t)q * 4096 + (size_t)(k * 16 + (m >> 2)) * 4 + (m & 3)];
        h[j] = f2bf(v); l[j] = f2bf(v - bf2f(h[j]));
    }
    size_t base = (size_t)q * 8192 + ((size_t)(k0 * 4 + mt) * 2) * 512 + lane * 8;
    *(us4*)(Op3 + base)       = *(us4*)&h[0];
    *(us4*)(Op3 + base + 4)   = *(us4*)&h[4];
    *(us4*)(Op3 + base + 512) = *(us4*)&l[0];
    *(us4*)(Op3 + base + 516) = *(us4*)&l[4];
}

// ---- site 0 (env0 = delta): env1 built by a cheap chain -> env plane ----
__global__ void s0_g2(const float* __restrict__ state, const float* __restrict__ layer,
                      float* __restrict__ g2) {
    int t = blockIdx.x * 256 + threadIdx.x;          // 16384: [A][j][L]
    int A = t >> 8, j = (t >> 4) & 15, L = t & 15;
    float s = 0;
    for (int i = 0; i < 16; i++) s += state[i * 64 + A] * layer[(j * 16 + i) * 16 + L];
    g2[t] = s;
}
__global__ void s0_g3(const float* __restrict__ g2, const float* __restrict__ oper,
                      float* __restrict__ g3) {
    int t = blockIdx.x * 256 + threadIdx.x;          // 65536: [A][L][k][O]
    int A = t >> 10, L = (t >> 6) & 15, k = (t >> 2) & 15, O = t & 3;
    float s = 0;
    for (int j = 0; j < 16; j++) s += g2[A * 256 + j * 16 + L] * oper[(j * 16 + k) * 4 + O];
    g3[t] = s;
}
__global__ void s0_g4(const float* __restrict__ g3, const float* __restrict__ layer,
                      float* __restrict__ g4) {
    int t = blockIdx.x * 256 + threadIdx.x;          // 1048576: [A][L][O][s][M]
    int A = t >> 14, L = (t >> 10) & 15, O = (t >> 8) & 3, sp = (t >> 4) & 15, M = t & 15;
    float s = 0;
    for (int k = 0; k < 16; k++)
        s += g3[A * 1024 + L * 64 + k * 4 + O] * layer[(k * 16 + sp) * 16 + M];
    g4[t] = s;
}
__global__ void s0_env(const float* __restrict__ g4, const float* __restrict__ state,
                       unsigned* __restrict__ envP) {
    int t = blockIdx.x * 256 + threadIdx.x;          // 4194304: [A][L][O][M][B]
    int A = t >> 16, L = (t >> 12) & 15, O = (t >> 10) & 3, M = (t >> 6) & 15, B = t & 63;
    float s = 0;
    for (int sp = 0; sp < 16; sp++)
        s += g4[A * 16384 + L * 1024 + O * 256 + sp * 16 + M] * state[sp * 64 + B];
    envP[(size_t)(A >> 5) * 2097152 + (size_t)(t & 65535) * 32 + (A & 31)] = split2(s);
}

// ---- site 7 chain (fp32) + fused dot ------------------------------------
__global__ void s7_c1(const float* __restrict__ state, const float* __restrict__ layer,
                      float* __restrict__ c1) {
    int t = blockIdx.x * 256 + threadIdx.x;          // 16384: [l][a][j]
    int l = t >> 10, a = (t >> 4) & 63, j = t & 15;
    float s = 0;
    for (int i = 0; i < 16; i++)
        s += state[7 * 65536 + (a * 16 + i) * 64] * layer[7 * 65536 + ((l * 16 + j) * 16 + i) * 16];
    c1[t] = s;
}
__global__ void s7_c2(const float* __restrict__ c1, const float* __restrict__ oper,
                      float* __restrict__ c2) {
    int t = blockIdx.x * 256 + threadIdx.x;          // 65536: [o][l][a][k]
    int o = t >> 14, l = (t >> 10) & 15, a = (t >> 4) & 63, k = t & 15;
    float s = 0;
    for (int j = 0; j < 16; j++)
        s += c1[l * 1024 + a * 16 + j] * oper[7 * 4096 + ((o * 16 + j) * 16 + k) * 4];
    c2[t] = s;
}
__global__ void s7_c3(const float* __restrict__ c2, const float* __restrict__ layer,
                      float* __restrict__ c3) {
    int t = blockIdx.x * 256 + threadIdx.x;          // 1048576: [m][o][l][a][s]
    int m = t >> 16, o = (t >> 14) & 3, l = (t >> 10) & 15, a = (t >> 4) & 63, sp = t & 15;
    float s = 0;
    for (int k = 0; k < 16; k++)
        s += c2[o * 16384 + l * 1024 + a * 16 + k] *
             layer[7 * 65536 + ((m * 16 + k) * 16 + sp) * 16];
    c3[t] = s;
}
__global__ void prep_sv(const float* __restrict__ state, float* __restrict__ sv) {
    int t = blockIdx.x * 256 + threadIdx.x;          // 1024: [b][sp]
    sv[t] = state[7 * 65536 + t * 64];
}
// out += sum_{a,n} env7[a][n] * sum_sp c3[lom(a-slice)][sp] * sv[b][sp]
__global__ __launch_bounds__(256) void s7_fused(const unsigned* __restrict__ envP,
                                                const float* __restrict__ c3,
                                                const float* __restrict__ sv,
                                                float* __restrict__ out) {
    __shared__ float c3s[1024], svs[1024], red[256];
    int t = threadIdx.x;
    int n0 = blockIdx.x * 64;            // 1024 blocks; n=(l,o,m,b), b spans 64
    int l = n0 >> 12, o = (n0 >> 10) & 3, m = (n0 >> 6) & 15;
    const float* c3b = c3 + m * 65536 + o * 16384 + l * 1024;   // [a][sp]
    for (int i = t; i < 1024; i += 256) { c3s[i] = c3b[i]; svs[i] = sv[i]; }
    __syncthreads();
    float s = 0;
    int a_lo = t & 31, hi = t >> 5;
#pragma unroll
    for (int g = 0; g < 8; g++) {
        int b = hi + g * 8;
        int n = n0 + b;
#pragma unroll
        for (int ab = 0; ab < 2; ab++) {
            unsigned u = envP[(size_t)ab * 2097152 + (size_t)n * 32 + a_lo];
            float e = bf2f((unsigned short)u) + bf2f((unsigned short)(u >> 16));
            int a = ab * 32 + a_lo;
            float w = 0;
#pragma unroll
            for (int sp = 0; sp < 16; sp++) w += c3s[a * 16 + sp] * svs[b * 16 + sp];
            s += e * w;
        }
    }
    red[t] = s; __syncthreads();
    for (int off = 128; off; off >>= 1) { if (t < off) red[t] += red[t + off]; __syncthreads(); }
    if (t == 0) atomicAdd(out, red[0]);
}

// ---- unified bf16x3 MFMA plane-GEMM --------------------------------------
// C[m,n] = sum_k Amat[k,m] * B[k,n]; B plane [k/32][n][k%32] u32 (h|l<<16).
// Block: 4 waves as WM x WN; wave tile 64m x 64n (4x4 of 16x16x32 MFMAs).
// LDS frag layout: slot(n,quad) = ((wn*4+quad)*4+nt)*16+lr -> b128 reads are
// lane-sequential (conflict-free).
template <int MT, int WM, int WN, int KT, int SM>
__global__ __launch_bounds__(256) void gemm_mx(const unsigned* __restrict__ Bp,
                                               const unsigned short* __restrict__ Ap,
                                               unsigned* __restrict__ Cu, int A0) {
    constexpr int BN = WN * 64;
    __shared__ unsigned short Bs_h[BN * 32];
    __shared__ unsigned short Bs_l[BN * 32];
    const int tid = threadIdx.x, lane = tid & 63, wave = tid >> 6;
    const int wm = wave / WN, wn = wave % WN;
    const int quad = lane >> 4, lr = lane & 15;
    const int n0 = blockIdx.x * BN;
    const size_t kstride = (size_t)gridDim.x * BN * 32;

    f32x4 acc[4][4];
#pragma unroll
    for (int i = 0; i < 4; i++)
#pragma unroll
        for (int j = 0; j < 4; j++)
#pragma unroll
            for (int r = 0; r < 4; r++) acc[i][j][r] = 0.0f;

    for (int k0 = 0; k0 < KT; k0++) {
        const unsigned* src = Bp + (size_t)k0 * kstride + (size_t)n0 * 32;
        constexpr int NV = BN / 32;          // uint4 per thread
#pragma unroll
        for (int v = 0; v < NV; v++) {
            int e = tid + v * 256;
            uint4 u = ((const uint4*)src)[e];
            int nl = e >> 3;
            int kk = (e & 7) * 4;            // multiple of 4, one quad per uint4
            int slot = (((nl >> 6) * 4 + (kk >> 3)) * 4 + ((nl >> 4) & 3)) * 16 + (nl & 15);
            int base = slot * 8 + (kk & 7);
            us4 hv, lv;
            hv[0] = (unsigned short)u.x; lv[0] = (unsigned short)(u.x >> 16);
            hv[1] = (unsigned short)u.y; lv[1] = (unsigned short)(u.y >> 16);
            hv[2] = (unsigned short)u.z; lv[2] = (unsigned short)(u.z >> 16);
            hv[3] = (unsigned short)u.w; lv[3] = (unsigned short)(u.w >> 16);
            *(us4*)(&Bs_h[base]) = hv;
            *(us4*)(&Bs_l[base]) = lv;
        }
        __syncthreads();

        bf16x8 ah[4], al[4];
#pragma unroll
        for (int mt = 0; mt < 4; mt++) {
            int gmt = blockIdx.y * (WM * 4) + wm * 4 + mt;
            const unsigned short* ap = Ap + ((size_t)(k0 * MT + gmt) * 2) * 512 + lane * 8;
            ah[mt] = *(const bf16x8*)ap;
            al[mt] = *(const bf16x8*)(ap + 512);
        }
#pragma unroll
        for (int nt = 0; nt < 4; nt++) {
            int slot = ((wn * 4 + quad) * 4 + nt) * 16 + lr;
            bf16x8 bh = *(bf16x8*)(&Bs_h[slot * 8]);
            bf16x8 bl = *(bf16x8*)(&Bs_l[slot * 8]);
#pragma unroll
            for (int mt = 0; mt < 4; mt++) {
                acc[mt][nt] = __builtin_amdgcn_mfma_f32_16x16x32_bf16(ah[mt], bh, acc[mt][nt], 0, 0, 0);
                acc[mt][nt] = __builtin_amdgcn_mfma_f32_16x16x32_bf16(ah[mt], bl, acc[mt][nt], 0, 0, 0);
                acc[mt][nt] = __builtin_amdgcn_mfma_f32_16x16x32_bf16(al[mt], bh, acc[mt][nt], 0, 0, 0);
            }
        }
        __syncthreads();
    }

#pragma unroll
    for (int mt = 0; mt < 4; mt++)
#pragma unroll
        for (int nt = 0; nt < 4; nt++)
#pragma unroll
            for (int r = 0; r < 4; r++) {
                int m = (blockIdx.y * (WM * 4) + wm * 4 + mt) * 16 + quad * 4 + r;
                int n = n0 + wn * 64 + nt * 16 + lr;
                unsigned kp; size_t addr;
                if constexpr (SM == 1) {        // -> t1 plane
                    kp = ((n >> 12) << 4) + (m >> 4);
                    addr = (size_t)(kp >> 5) * 2097152 +
                           (size_t)((n & 4095) * 16 + (m & 15)) * 32 + (kp & 31);
                } else if constexpr (SM == 2) { // -> t2 plane
                    kp = ((n >> 14) << 4) + (m >> 4);
                    addr = (size_t)(kp >> 5) * 8388608 +
                           (size_t)((m & 15) * 16384 + (n & 16383)) * 32 + (kp & 31);
                } else if constexpr (SM == 3) { // -> t3 plane
                    kp = (((n >> 10) & 15) << 4) + (m >> 2);
                    addr = (size_t)(kp >> 5) * 2097152 +
                           (size_t)((m & 3) * 16384 + ((n >> 4) & 63) * 256 +
                                    ((n >> 14) << 4) + (n & 15)) * 32 + (kp & 31);
                } else if constexpr (SM == 4) { // -> t4 plane
                    kp = (((n >> 8) & 63) << 4) + (m >> 4);
                    addr = (size_t)(kp >> 5) * 524288 +
                           (size_t)((m & 15) * 1024 + ((n >> 4) & 15) * 64 +
                                    ((n >> 14) << 4) + (n & 15)) * 32 + (kp & 31);
                } else {                        // SM == 5 -> env' plane
                    kp = A0 + (n & 15);
                    addr = (size_t)(kp >> 5) * 2097152 +
                           (size_t)(((n >> 6) & 15) * 4096 + ((n >> 4) & 3) * 1024 +
                                    (n >> 10) * 64 + m) * 32 + (kp & 31);
                }
                Cu[addr] = split2(acc[mt][nt][r]);
            }
}

extern "C" void kernel_launch(void* const* d_in, const int* in_sizes, int n_in,
                              void* d_out, int out_size, void* d_ws, size_t ws_size,
                              hipStream_t stream) {
    const float* state = (const float*)d_in[0];   // [8,64,16,64]
    const float* layer = (const float*)d_in[1];   // [1,8,16,16,16,16]
    const float* oper  = (const float*)d_in[2];   // [8,4,16,16,4]
    float* out = (float*)d_out;

    const size_t need = (16777216ull * 2 + 4194304ull * 2) * 4ull +
                        (1048576ull * 4 + 65536ull) * 2ull + 4096ull;
    if (ws_size < need) {
        write_diag_kernel<<<1, 64, 0, stream>>>(out, (float)ws_size);
        return;
    }
    unsigned* P1    = (unsigned*)d_ws;
    unsigned* P2    = P1 + 16777216;
    unsigned* envPA = P2 + 16777216;
    unsigned* envPB = envPA + 4194304;
    unsigned short* Ap2 = (unsigned short*)(envPB + 4194304);
    unsigned short* Ap4 = Ap2 + 1048576;
    unsigned short* Sp1 = Ap4 + 1048576;
    unsigned short* Sp5 = Sp1 + 1048576;
    unsigned short* Op3 = Sp5 + 1048576;
    float* sv  = (float*)(Op3 + 65536);
    float* SCR = (float*)P1;   // boundary-chain fp32 scratch (P1 free then)

    prep_apack<<<256, 256, 0, stream>>>(layer, Ap2, Ap4);
    prep_spack1<<<256, 256, 0, stream>>>(state, Sp1);
    prep_spack5<<<256, 256, 0, stream>>>(state, Sp5);
    prep_opack3<<<16, 256, 0, stream>>>(oper, Op3);
    prep_sv<<<4, 256, 0, stream>>>(state, sv);

    // site 0 -> envPB (exact fp32 until the final plane split)
    s0_g2<<<64, 256, 0, stream>>>(state, layer, SCR);
    s0_g3<<<256, 256, 0, stream>>>(SCR, oper, SCR + 16384);
    s0_g4<<<4096, 256, 0, stream>>>(SCR + 16384, layer, SCR + 81920);
    s0_env<<<16384, 256, 0, stream>>>(SCR + 81920, state, envPB);

    for (int q = 1; q < 7; q++) {
        unsigned* ein  = (q & 1) ? envPB : envPA;
        unsigned* eout = (q & 1) ? envPA : envPB;
        for (int c = 0; c < 4; c++) {
            gemm_mx<16, 2, 2, 2, 1><<<dim3(512, 2), 256, 0, stream>>>(
                ein, Sp1 + (size_t)(q * 4 + c) * 32768, P1, 0);
            gemm_mx<16, 2, 2, 8, 2><<<dim3(512, 2), 256, 0, stream>>>(
                P1, Ap2 + (size_t)q * 131072, P2, 0);
            gemm_mx<4, 1, 4, 2, 3><<<dim3(1024, 1), 256, 0, stream>>>(
                P2, Op3 + (size_t)q * 8192, P1, 0);
            gemm_mx<16, 2, 2, 8, 4><<<dim3(512, 2), 256, 0, stream>>>(
                P1, Ap4 + (size_t)q * 131072, P2, 0);
            gemm_mx<4, 1, 4, 32, 5><<<dim3(64, 1), 256, 0, stream>>>(
                P2, Sp5 + (size_t)q * 131072, eout, c * 16);
        }
    }

    // site 7: out = <env7 (plane, in envPB), w> with w built on the fly
    s7_c1<<<64, 256, 0, stream>>>(state, layer, SCR);
    s7_c2<<<256, 256, 0, stream>>>(SCR, oper, SCR + 16384);
    s7_c3<<<4096, 256, 0, stream>>>(SCR + 16384, layer, SCR + 81920);
    zero_out<<<1, 64, 0, stream>>>(out);
    s7_fused<<<1024, 256, 0, stream>>>(envPB, SCR + 81920, sv, out);
}

// Round 5
// 5313.466 us; speedup vs baseline: 2.3438x; 2.3438x over previous
//
#include <hip/hip_runtime.h>

// ---------------------------------------------------------------------------
// <psi|U^dag O U|psi>, NQ=8, r=64 d=16 rl=16 ro=4.
// R5 = R3 structure (5.94 ms, verified) + two fixes:
//  (a) G2/G4 MFMA kernel single-pass: one block covers all M=256 (4 waves x
//      64m), B strip read ONCE (was twice), LDS pad 32->40 kills staging bank
//      conflicts. BN=64, grid 1024.
//  (b) site-7 w-build + dot fused into one LDS-staged kernel (was 300 us
//      latency-bound s7_w).
// Data flow per (site q=1..6, A-chunk c=0..3):
//   G1 (fp32 vec)  env x S      -> P  (u32 plane: bf16 hi|lo<<16, [k/32][n][k%32])
//   G2 (MFMA x3)   Ud-pack x P  -> F  (fp32 t2 [64][262144])
//   G3 (fp32 vec)  O x F        -> P  (u32 plane t3)
//   G4 (MFMA x3)   U-pack  x P  -> F  (fp32 t4 [1024][16384])
//   G5 (fp32 vec)  S x F        -> env' (fp32 [a][lomb])
// ---------------------------------------------------------------------------

typedef __attribute__((ext_vector_type(8))) short bf16x8;
typedef __attribute__((ext_vector_type(4))) float f32x4;
typedef __attribute__((ext_vector_type(4))) unsigned short us4;

static __device__ __forceinline__ unsigned short f2bf(float x) {
    union { float f; unsigned u; } a; a.f = x;
    return (unsigned short)((a.u + 0x7FFF + ((a.u >> 16) & 1)) >> 16);
}
static __device__ __forceinline__ float bf2f(unsigned short h) {
    union { unsigned u; float f; } a; a.u = (unsigned)h << 16; return a.f;
}
static __device__ __forceinline__ unsigned split2(float x) {
    unsigned short h = f2bf(x);
    unsigned short l = f2bf(x - bf2f(h));
    return (unsigned)h | ((unsigned)l << 16);
}

__global__ void write_diag_kernel(float* out, float v) {
    if (threadIdx.x == 0 && blockIdx.x == 0) out[0] = v;
}
__global__ void zero_out(float* o) {
    if (threadIdx.x == 0 && blockIdx.x == 0) o[0] = 0.0f;
}

// ---- A-operand fragment packs for G2 (Ud) and G4 (U) --------------------
// Layout: [(q*8+k0)*16+mt][hl][lane][8]; frag k = k0*32+quad*8+j, m = mt*16+(lane&15)
__global__ void prep_apack(const float* __restrict__ layer,
                           unsigned short* __restrict__ Ap2,
                           unsigned short* __restrict__ Ap4) {
    int idx = blockIdx.x * 256 + threadIdx.x;   // 65536
    int q = idx >> 13, k0 = (idx >> 10) & 7, mt = (idx >> 6) & 15, lane = idx & 63;
    int quad = lane >> 4, r = lane & 15;
    unsigned short h2[8], l2[8], h4[8], l4[8];
#pragma unroll
    for (int j = 0; j < 8; j++) {
        int k = k0 * 32 + quad * 8 + j;
        int m = mt * 16 + r;
        // G2: Amat[k=(l,i)][m=(j2,L)] = layer[q][l][j2][i][L]
        float v2 = layer[(size_t)q * 65536 +
                         (size_t)((((k >> 4) * 16 + (m >> 4)) * 16 + (k & 15)) * 16 + (m & 15))];
        // G4: Amat[k=(m2,k2)][m=(s,M)] = layer[q][m2][k2][s][M]
        float v4 = layer[(size_t)q * 65536 +
                         (size_t)((((k >> 4) * 16 + (k & 15)) * 16 + (m >> 4)) * 16 + (m & 15))];
        h2[j] = f2bf(v2); l2[j] = f2bf(v2 - bf2f(h2[j]));
        h4[j] = f2bf(v4); l4[j] = f2bf(v4 - bf2f(h4[j]));
    }
    size_t base = ((size_t)((q * 8 + k0) * 16 + mt) * 2) * 512 + lane * 8;
    *(us4*)(Ap2 + base)       = *(us4*)&h2[0];
    *(us4*)(Ap2 + base + 4)   = *(us4*)&h2[4];
    *(us4*)(Ap2 + base + 512) = *(us4*)&l2[0];
    *(us4*)(Ap2 + base + 516) = *(us4*)&l2[4];
    *(us4*)(Ap4 + base)       = *(us4*)&h4[0];
    *(us4*)(Ap4 + base + 4)   = *(us4*)&h4[4];
    *(us4*)(Ap4 + base + 512) = *(us4*)&l4[0];
    *(us4*)(Ap4 + base + 516) = *(us4*)&l4[4];
}

// ---- site 0 (env0 = delta): env1 built by a cheap chain (fp32 exact) ----
__global__ void s0_g2(const float* __restrict__ state, const float* __restrict__ layer,
                      float* __restrict__ g2) {
    int t = blockIdx.x * 256 + threadIdx.x;          // 16384: [A][j][L]
    int A = t >> 8, j = (t >> 4) & 15, L = t & 15;
    float s = 0;
    for (int i = 0; i < 16; i++) s += state[i * 64 + A] * layer[(j * 16 + i) * 16 + L];
    g2[t] = s;
}
__global__ void s0_g3(const float* __restrict__ g2, const float* __restrict__ oper,
                      float* __restrict__ g3) {
    int t = blockIdx.x * 256 + threadIdx.x;          // 65536: [A][L][k][O]
    int A = t >> 10, L = (t >> 6) & 15, k = (t >> 2) & 15, O = t & 3;
    float s = 0;
    for (int j = 0; j < 16; j++) s += g2[A * 256 + j * 16 + L] * oper[(j * 16 + k) * 4 + O];
    g3[t] = s;
}
__global__ void s0_g4(const float* __restrict__ g3, const float* __restrict__ layer,
                      float* __restrict__ g4) {
    int t = blockIdx.x * 256 + threadIdx.x;          // 1048576: [A][L][O][s][M]
    int A = t >> 14, L = (t >> 10) & 15, O = (t >> 8) & 3, sp = (t >> 4) & 15, M = t & 15;
    float s = 0;
    for (int k = 0; k < 16; k++)
        s += g3[A * 1024 + L * 64 + k * 4 + O] * layer[(k * 16 + sp) * 16 + M];
    g4[t] = s;
}
__global__ void s0_env(const float* __restrict__ g4, const float* __restrict__ state,
                       float* __restrict__ env) {
    int t = blockIdx.x * 256 + threadIdx.x;          // 4194304: [A][L][O][M][B]
    int A = t >> 16, L = (t >> 12) & 15, O = (t >> 10) & 3, M = (t >> 6) & 15, B = t & 63;
    float s = 0;
    for (int sp = 0; sp < 16; sp++)
        s += g4[A * 16384 + L * 1024 + O * 256 + sp * 16 + M] * state[sp * 64 + B];
    env[t] = s;
}

// ---- site 7 chain (fp32) + fused dot ------------------------------------
__global__ void s7_c1(const float* __restrict__ state, const float* __restrict__ layer,
                      float* __restrict__ c1) {
    int t = blockIdx.x * 256 + threadIdx.x;          // 16384: [l][a][j]
    int l = t >> 10, a = (t >> 4) & 63, j = t & 15;
    float s = 0;
    for (int i = 0; i < 16; i++)
        s += state[7 * 65536 + (a * 16 + i) * 64] * layer[7 * 65536 + ((l * 16 + j) * 16 + i) * 16];
    c1[t] = s;
}
__global__ void s7_c2(const float* __restrict__ c1, const float* __restrict__ oper,
                      float* __restrict__ c2) {
    int t = blockIdx.x * 256 + threadIdx.x;          // 65536: [o][l][a][k]
    int o = t >> 14, l = (t >> 10) & 15, a = (t >> 4) & 63, k = t & 15;
    float s = 0;
    for (int j = 0; j < 16; j++)
        s += c1[l * 1024 + a * 16 + j] * oper[7 * 4096 + ((o * 16 + j) * 16 + k) * 4];
    c2[t] = s;
}
__global__ void s7_c3(const float* __restrict__ c2, const float* __restrict__ layer,
                      float* __restrict__ c3) {
    int t = blockIdx.x * 256 + threadIdx.x;          // 1048576: [m][o][l][a][s]
    int m = t >> 16, o = (t >> 14) & 3, l = (t >> 10) & 15, a = (t >> 4) & 63, sp = t & 15;
    float s = 0;
    for (int k = 0; k < 16; k++)
        s += c2[o * 16384 + l * 1024 + a * 16 + k] *
             layer[7 * 65536 + ((m * 16 + k) * 16 + sp) * 16];
    c3[t] = s;
}
__global__ void prep_sv(const float* __restrict__ state, float* __restrict__ sv) {
    int t = blockIdx.x * 256 + threadIdx.x;          // 1024: [b][sp]
    sv[t] = state[7 * 65536 + t * 64];
}
// out += sum_{a,b} env7[a][n0+b] * (sum_sp c3[m,o,l,a,sp] * sv[b,sp])
__global__ __launch_bounds__(256) void s7_fused(const float* __restrict__ env,
                                                const float* __restrict__ c3,
                                                const float* __restrict__ sv,
                                                float* __restrict__ out) {
    __shared__ float c3s[1024], svs[1024], red[256];
    int t = threadIdx.x;
    int n0 = blockIdx.x * 64;            // 1024 blocks; n=(l,o,m,b)
    int l = n0 >> 12, o = (n0 >> 10) & 3, m = (n0 >> 6) & 15;
    const float* c3b = c3 + m * 65536 + o * 16384 + l * 1024;   // [a][sp]
    for (int i = t; i < 1024; i += 256) { c3s[i] = c3b[i]; svs[i] = sv[i]; }
    __syncthreads();
    float s = 0;
    int b = t & 63, ag = t >> 6;
#pragma unroll
    for (int g = 0; g < 16; g++) {
        int a = ag * 16 + g;
        float e = env[(size_t)a * 65536 + n0 + b];
        float w = 0;
#pragma unroll
        for (int sp = 0; sp < 16; sp++) w += c3s[a * 16 + sp] * svs[b * 16 + sp];
        s += e * w;
    }
    red[t] = s; __syncthreads();
    for (int off = 128; off; off >>= 1) { if (t < off) red[t] += red[t + off]; __syncthreads(); }
    if (t == 0) atomicAdd(out, red[0]);
}

// ---- fp32 vector GEMM (G1 / G3 / G5), C = A^T[KxM] * B[KxN] --------------
template <int BM, int BN, int BK, int TM, int TN, int SM, int BL>
__global__ __launch_bounds__(256) void gemm_tn(const float* __restrict__ A,
                                               const float* __restrict__ B,
                                               float* __restrict__ Cf,
                                               unsigned* __restrict__ Cu,
                                               int M, int N, int K, int A0) {
    constexpr int TNB = BN / TN;
    constexpr int TMB = BM / TM;
    static_assert(TNB * TMB == 256, "block must be 256 threads");
    __shared__ float As[BK * BM];
    __shared__ float Bs[BK * BN];

    const int tid = threadIdx.x;
    const int tx = tid % TNB, ty = tid / TNB;
    const int n0 = blockIdx.x * BN, m0 = blockIdx.y * BM;

    float acc[TM][TN];
#pragma unroll
    for (int i = 0; i < TM; i++)
#pragma unroll
        for (int j = 0; j < TN; j++) acc[i][j] = 0.0f;

    for (int k0 = 0; k0 < K; k0 += BK) {
        constexpr int AV = (BK * BM) / (256 * 4);
#pragma unroll
        for (int v = 0; v < AV; v++) {
            int e = (tid + v * 256) * 4;
            int kk = e / BM, mm = e % BM;
            *(float4*)(As + kk * BM + mm) =
                *(const float4*)(A + (size_t)(k0 + kk) * M + (m0 + mm));
        }
        constexpr int BV = (BK * BN) / (256 * 4);
#pragma unroll
        for (int v = 0; v < BV; v++) {
            int e = (tid + v * 256) * 4;
            int kk = e / BN, nn = e % BN;
            const float* src;
            if constexpr (BL == 0) {
                src = B + (size_t)(k0 + kk) * N + (n0 + nn);
            } else {
                int gn = n0 + nn;
                src = B + (size_t)(k0 + kk) * 1024 + (gn >> 4) * 64 + A0 + (gn & 15);
            }
            *(float4*)(Bs + kk * BN + nn) = *(const float4*)src;
        }
        __syncthreads();
#pragma unroll
        for (int k = 0; k < BK; k++) {
            float a[TM], b[TN];
#pragma unroll
            for (int i = 0; i < TM; i += 4)
                *(float4*)(a + i) = *(float4*)(As + k * BM + ty * TM + i);
#pragma unroll
            for (int j = 0; j < TN; j += 4)
                *(float4*)(b + j) = *(float4*)(Bs + k * BN + tx * TN + j);
#pragma unroll
            for (int i = 0; i < TM; i++)
#pragma unroll
                for (int j = 0; j < TN; j++) acc[i][j] += a[i] * b[j];
        }
        __syncthreads();
    }

#pragma unroll
    for (int i = 0; i < TM; i++) {
        int m = m0 + ty * TM + i;
#pragma unroll
        for (int j = 0; j < TN; j++) {
            int n = n0 + tx * TN + j;
            if constexpr (SM == 1) {
                // m=(l,o,m2,b), n=(i2,a4) -> t1 plane, k=(l,i2), nn=(o,m2,b,a4)
                int kn = ((m >> 12) << 4) + (n >> 4);
                int nn = (m & 4095) * 16 + (n & 15);
                Cu[(size_t)(kn >> 5) * 2097152 + (size_t)nn * 32 + (kn & 31)] =
                    split2(acc[i][j]);
            } else if constexpr (SM == 3) {
                // m=(k,O2), n=(L,m2,b,a4) -> t3 plane, k=(m2,k), nn=(O2,b,L,a4)
                int kn = (((n >> 10) & 15) << 4) + (m >> 2);
                int nn = (m & 3) * 16384 + ((n >> 4) & 63) * 256 + ((n >> 14) << 4) + (n & 15);
                Cu[(size_t)(kn >> 5) * 2097152 + (size_t)nn * 32 + (kn & 31)] =
                    split2(acc[i][j]);
            } else {
                // m=B, n=(M2,L,O2,a4) -> env'[A0+a4][L][O][M][B] fp32
                Cf[(size_t)(A0 + (n & 15)) * 65536 + ((n >> 6) & 15) * 4096 +
                   ((n >> 4) & 3) * 1024 + (n >> 10) * 64 + m] = acc[i][j];
            }
        }
    }
}

// ---- bf16x3 MFMA GEMM for G2/G4: M=256, N=65536, K=256, single m-pass ----
// One block = 4 waves, wave wm covers m = wm*64..+63; BN=64 so each B strip
// is read exactly once. B plane [k/32][n][k%32] u32 (h|l<<16). LDS row pad
// 32->40 u16 kills staging/frag bank conflicts.
template <int SM>
__global__ __launch_bounds__(256) void gemm_mfma2(const unsigned* __restrict__ Bp,
                                                  const unsigned short* __restrict__ Ap,
                                                  float* __restrict__ C) {
    __shared__ unsigned short Bs_h[64 * 40];   // [n(64)][kk(32)+pad8]
    __shared__ unsigned short Bs_l[64 * 40];
    const int tid = threadIdx.x;
    const int lane = tid & 63, wm = tid >> 6;
    const int quad = lane >> 4, lr = lane & 15;
    const int n0 = blockIdx.x * 64;

    f32x4 acc[4][4];
#pragma unroll
    for (int i = 0; i < 4; i++)
#pragma unroll
        for (int j = 0; j < 4; j++)
#pragma unroll
            for (int r = 0; r < 4; r++) acc[i][j][r] = 0.0f;

    for (int k0 = 0; k0 < 8; k0++) {
        // stage B tile 64n x 32k (8 KB of u32), 2 uint4 per thread, coalesced
        const unsigned* src = Bp + (size_t)k0 * 2097152 + (size_t)n0 * 32;
#pragma unroll
        for (int v = 0; v < 2; v++) {
            int e = tid * 2 + v;
            uint4 u = ((const uint4*)src)[e];
            int nl = e >> 3, k4 = (e & 7) * 4;
            int base = nl * 40 + k4;
            us4 hv, lv;
            hv[0] = (unsigned short)u.x; lv[0] = (unsigned short)(u.x >> 16);
            hv[1] = (unsigned short)u.y; lv[1] = (unsigned short)(u.y >> 16);
            hv[2] = (unsigned short)u.z; lv[2] = (unsigned short)(u.z >> 16);
            hv[3] = (unsigned short)u.w; lv[3] = (unsigned short)(u.w >> 16);
            *(us4*)(&Bs_h[base]) = hv;
            *(us4*)(&Bs_l[base]) = lv;
        }
        __syncthreads();

        bf16x8 ah[4], al[4];
#pragma unroll
        for (int mt = 0; mt < 4; mt++) {
            int gmt = wm * 4 + mt;
            const unsigned short* ap = Ap + ((size_t)(k0 * 16 + gmt) * 2) * 512 + lane * 8;
            ah[mt] = *(const bf16x8*)ap;
            al[mt] = *(const bf16x8*)(ap + 512);
        }
#pragma unroll
        for (int nt = 0; nt < 4; nt++) {
            int nl = nt * 16 + lr;
            bf16x8 bh = *(bf16x8*)(&Bs_h[nl * 40 + quad * 8]);
            bf16x8 bl = *(bf16x8*)(&Bs_l[nl * 40 + quad * 8]);
#pragma unroll
            for (int mt = 0; mt < 4; mt++) {
                acc[mt][nt] = __builtin_amdgcn_mfma_f32_16x16x32_bf16(ah[mt], bh, acc[mt][nt], 0, 0, 0);
                acc[mt][nt] = __builtin_amdgcn_mfma_f32_16x16x32_bf16(ah[mt], bl, acc[mt][nt], 0, 0, 0);
                acc[mt][nt] = __builtin_amdgcn_mfma_f32_16x16x32_bf16(al[mt], bh, acc[mt][nt], 0, 0, 0);
            }
        }
        __syncthreads();
    }

#pragma unroll
    for (int mt = 0; mt < 4; mt++)
#pragma unroll
        for (int nt = 0; nt < 4; nt++)
#pragma unroll
            for (int r = 0; r < 4; r++) {
                int m = (wm * 4 + mt) * 16 + quad * 4 + r;
                int n = n0 + nt * 16 + lr;
                size_t addr;
                if constexpr (SM == 2)   // t2[(o,j)][L][m2,b,a4]
                    addr = (size_t)((n >> 14) * 16 + (m >> 4)) * 262144 +
                           (m & 15) * 16384 + (n & 16383);
                else                     // t4[(b,s)][M][L][O][a4]
                    addr = (size_t)(((n >> 8) & 63) * 16 + (m >> 4)) * 16384 +
                           (m & 15) * 1024 + ((n >> 4) & 15) * 64 + ((n >> 14) << 4) + (n & 15);
                C[addr] = acc[mt][nt][r];
            }
}

extern "C" void kernel_launch(void* const* d_in, const int* in_sizes, int n_in,
                              void* d_out, int out_size, void* d_ws, size_t ws_size,
                              hipStream_t stream) {
    const float* state = (const float*)d_in[0];   // [8,64,16,64]
    const float* layer = (const float*)d_in[1];   // [1,8,16,16,16,16]
    const float* oper  = (const float*)d_in[2];   // [8,4,16,16,4]
    float* out = (float*)d_out;

    // ws: F(16.8M f32) | P(16.8M u32) | envA | envB | Ap2 | Ap4 | sv
    const size_t need = (16777216ull + 16777216ull + 2 * 4194304ull) * 4ull +
                        2 * 2097152ull + 4096ull;
    if (ws_size < need) {
        write_diag_kernel<<<1, 64, 0, stream>>>(out, (float)ws_size);
        return;
    }
    float* F    = (float*)d_ws;
    unsigned* P = (unsigned*)(F + 16777216);
    float* envA = (float*)(P + 16777216);
    float* envB = envA + 4194304;
    unsigned short* Ap2 = (unsigned short*)(envB + 4194304);
    unsigned short* Ap4 = Ap2 + 1048576;
    float* sv = (float*)(Ap4 + 1048576);

    prep_apack<<<256, 256, 0, stream>>>(layer, Ap2, Ap4);
    prep_sv<<<4, 256, 0, stream>>>(state, sv);

    // site 0 -> envB (exact fp32)
    s0_g2<<<64, 256, 0, stream>>>(state, layer, F);
    s0_g3<<<256, 256, 0, stream>>>(F, oper, F + 16384);
    s0_g4<<<4096, 256, 0, stream>>>(F + 16384, layer, F + 81920);
    s0_env<<<16384, 256, 0, stream>>>(F + 81920, state, envB);

    for (int q = 1; q < 7; q++) {
        float* ein  = (q & 1) ? envB : envA;
        float* eout = (q & 1) ? envA : envB;
        const float* Sq = state + (size_t)q * 65536;
        const float* Oq = oper + (size_t)q * 4096;
        for (int c = 0; c < 4; c++) {
            int A0 = c * 16;
            gemm_tn<128, 128, 16, 8, 8, 1, 1><<<dim3(2, 512), 256, 0, stream>>>(
                ein, Sq, nullptr, P, 65536, 256, 64, A0);
            gemm_mfma2<2><<<1024, 256, 0, stream>>>(P, Ap2 + (size_t)q * 131072, F);
            gemm_tn<64, 128, 16, 4, 8, 3, 0><<<dim3(2048, 1), 256, 0, stream>>>(
                Oq, F, nullptr, P, 64, 262144, 64, 0);
            gemm_mfma2<4><<<1024, 256, 0, stream>>>(P, Ap4 + (size_t)q * 131072, F);
            gemm_tn<64, 64, 16, 4, 4, 5, 0><<<dim3(256, 1), 256, 0, stream>>>(
                Sq, F, eout, nullptr, 64, 16384, 1024, A0);
        }
    }

    // site 7: out = <env7 (fp32, in envB), w> with w built on the fly
    s7_c1<<<64, 256, 0, stream>>>(state, layer, F);
    s7_c2<<<256, 256, 0, stream>>>(F, oper, F + 16384);
    s7_c3<<<4096, 256, 0, stream>>>(F + 16384, layer, F + 81920);
    zero_out<<<1, 64, 0, stream>>>(out);
    s7_fused<<<1024, 256, 0, stream>>>(envB, F + 81920, sv, out);
}

// Round 6
// 5267.337 us; speedup vs baseline: 2.3643x; 1.0088x over previous
//
#include <hip/hip_runtime.h>

// ---------------------------------------------------------------------------
// <psi|U^dag O U|psi>, NQ=8, r=64 d=16 rl=16 ro=4.
// R6: all five chain GEMMs on bf16x3 MFMA via ONE templated kernel gemm_u:
//   - A operands pre-packed in MFMA fragment order (per site / chunk).
//   - B either pre-split u32 plane [k/32][n][k%32] (BFMT=0: G2,G4) or fp32
//     [k][n] with split-on-stage (BFMT=1: G1 env, G3 t2, G5 t4).
//   - register-prefetch software pipeline on the B tile.
// Tensor formats:
//   env  fp32 [a(64)][l,o,m2,b(65536)]
//   t1   u32 plane [k=(l,i)/32][o,m2,b,a4(65536)][k%32]   (G1 out, G2 in)
//   t2   fp32 [k=(o,j)(64)][L,m2,b,a4(262144)]            (G2 out, G3 in)
//   t3   u32 plane [k=(m2,k2)/32][O2,b,L,a4(65536)][k%32] (G3 out, G4 in)
//   t4   fp32 [k=(b,s)(1024)][M2,L,O2,a4(16384)]          (G4 out, G5 in)
// Boundary sites 0/7: cheap fp32 rank-structured chains (delta-closure).
// ---------------------------------------------------------------------------

typedef __attribute__((ext_vector_type(8))) short bf16x8;
typedef __attribute__((ext_vector_type(4))) float f32x4;
typedef __attribute__((ext_vector_type(4))) unsigned short us4;

static __device__ __forceinline__ unsigned short f2bf(float x) {
    union { float f; unsigned u; } a; a.f = x;
    return (unsigned short)((a.u + 0x7FFF + ((a.u >> 16) & 1)) >> 16);
}
static __device__ __forceinline__ float bf2f(unsigned short h) {
    union { unsigned u; float f; } a; a.u = (unsigned)h << 16; return a.f;
}
static __device__ __forceinline__ unsigned split2(float x) {
    unsigned short h = f2bf(x);
    unsigned short l = f2bf(x - bf2f(h));
    return (unsigned)h | ((unsigned)l << 16);
}

__global__ void write_diag_kernel(float* out, float v) {
    if (threadIdx.x == 0 && blockIdx.x == 0) out[0] = v;
}
__global__ void zero_out(float* o) {
    if (threadIdx.x == 0 && blockIdx.x == 0) o[0] = 0.0f;
}

// ---- A-operand fragment packs -------------------------------------------
// Pack layout: [(k0*MT+mt)*2+hl][lane(64)][8]; frag k = k0*32+quad*8+j,
// m = mt*16 + (lane&15).

// G2 (Ud) / G4 (U), MT=16, KT=8
__global__ void prep_apack(const float* __restrict__ layer,
                           unsigned short* __restrict__ Ap2,
                           unsigned short* __restrict__ Ap4) {
    int idx = blockIdx.x * 256 + threadIdx.x;   // 65536
    int q = idx >> 13, k0 = (idx >> 10) & 7, mt = (idx >> 6) & 15, lane = idx & 63;
    int quad = lane >> 4, r = lane & 15;
    unsigned short h2[8], l2[8], h4[8], l4[8];
#pragma unroll
    for (int j = 0; j < 8; j++) {
        int k = k0 * 32 + quad * 8 + j;
        int m = mt * 16 + r;
        // G2: Amat[k=(l,i)][m=(j2,L)] = layer[q][l][j2][i][L]
        float v2 = layer[(size_t)q * 65536 +
                         (size_t)((((k >> 4) * 16 + (m >> 4)) * 16 + (k & 15)) * 16 + (m & 15))];
        // G4: Amat[k=(m2,k2)][m=(s,M2)] = layer[q][m2][k2][s][M2]
        float v4 = layer[(size_t)q * 65536 +
                         (size_t)((((k >> 4) * 16 + (k & 15)) * 16 + (m >> 4)) * 16 + (m & 15))];
        h2[j] = f2bf(v2); l2[j] = f2bf(v2 - bf2f(h2[j]));
        h4[j] = f2bf(v4); l4[j] = f2bf(v4 - bf2f(h4[j]));
    }
    size_t base = ((size_t)((q * 8 + k0) * 16 + mt) * 2) * 512 + lane * 8;
    *(us4*)(Ap2 + base)       = *(us4*)&h2[0];
    *(us4*)(Ap2 + base + 4)   = *(us4*)&h2[4];
    *(us4*)(Ap2 + base + 512) = *(us4*)&l2[0];
    *(us4*)(Ap2 + base + 516) = *(us4*)&l2[4];
    *(us4*)(Ap4 + base)       = *(us4*)&h4[0];
    *(us4*)(Ap4 + base + 4)   = *(us4*)&h4[4];
    *(us4*)(Ap4 + base + 512) = *(us4*)&l4[0];
    *(us4*)(Ap4 + base + 516) = *(us4*)&l4[4];
}

// G1 (S as A): Amat[k=a][m=(i,a4)] = state[q][a][i][c*16+a4]; MT=16, KT=2
__global__ void prep_spack1(const float* __restrict__ state,
                            unsigned short* __restrict__ Sp1) {
    int idx = blockIdx.x * 256 + threadIdx.x;   // 65536
    int q = idx >> 13, c = (idx >> 11) & 3, k0 = (idx >> 10) & 1,
        mt = (idx >> 6) & 15, lane = idx & 63;
    int quad = lane >> 4, lr = lane & 15;
    unsigned short h[8], l[8];
#pragma unroll
    for (int j = 0; j < 8; j++) {
        int k = k0 * 32 + quad * 8 + j;
        float v = state[(size_t)q * 65536 + (size_t)(k * 16 + mt) * 64 + c * 16 + lr];
        h[j] = f2bf(v); l[j] = f2bf(v - bf2f(h[j]));
    }
    size_t base = (size_t)(q * 4 + c) * 32768 + ((size_t)(k0 * 16 + mt) * 2) * 512 + lane * 8;
    *(us4*)(Sp1 + base)       = *(us4*)&h[0];
    *(us4*)(Sp1 + base + 4)   = *(us4*)&h[4];
    *(us4*)(Sp1 + base + 512) = *(us4*)&l[0];
    *(us4*)(Sp1 + base + 516) = *(us4*)&l[4];
}

// G5 (S as A): Amat[k=(b,s)][m=B'] = state[q][b][s][B']; MT=4, KT=32
__global__ void prep_spack5(const float* __restrict__ state,
                            unsigned short* __restrict__ Sp5) {
    int idx = blockIdx.x * 256 + threadIdx.x;   // 65536
    int q = idx >> 13, k0 = (idx >> 8) & 31, mt = (idx >> 6) & 3, lane = idx & 63;
    int quad = lane >> 4, lr = lane & 15;
    unsigned short h[8], l[8];
#pragma unroll
    for (int j = 0; j < 8; j++) {
        int k = k0 * 32 + quad * 8 + j;
        float v = state[(size_t)q * 65536 + (size_t)k * 64 + mt * 16 + lr];
        h[j] = f2bf(v); l[j] = f2bf(v - bf2f(h[j]));
    }
    size_t base = (size_t)q * 131072 + ((size_t)(k0 * 4 + mt) * 2) * 512 + lane * 8;
    *(us4*)(Sp5 + base)       = *(us4*)&h[0];
    *(us4*)(Sp5 + base + 4)   = *(us4*)&h[4];
    *(us4*)(Sp5 + base + 512) = *(us4*)&l[0];
    *(us4*)(Sp5 + base + 516) = *(us4*)&l[4];
}

// G3 (O as A): Amat[k=(o,j2)][m=(k2,O2)] = oper[q][o][j2][k2][O2]; MT=4, KT=2
__global__ void prep_opack3(const float* __restrict__ oper,
                            unsigned short* __restrict__ Op3) {
    int idx = blockIdx.x * 256 + threadIdx.x;   // 4096
    int q = idx >> 9, k0 = (idx >> 8) & 1, mt = (idx >> 6) & 3, lane = idx & 63;
    int quad = lane >> 4, lr = lane & 15;
    unsigned short h[8], l[8];
#pragma unroll
    for (int j = 0; j < 8; j++) {
        int k = k0 * 32 + quad * 8 + j;
        int m = mt * 16 + lr;
        float v = oper[(size_t)q * 4096 + (size_t)(k * 16 + (m >> 2)) * 4 + (m & 3)];
        h[j] = f2bf(v); l[j] = f2bf(v - bf2f(h[j]));
    }
    size_t base = (size_t)q * 8192 + ((size_t)(k0 * 4 + mt) * 2) * 512 + lane * 8;
    *(us4*)(Op3 + base)       = *(us4*)&h[0];
    *(us4*)(Op3 + base + 4)   = *(us4*)&h[4];
    *(us4*)(Op3 + base + 512) = *(us4*)&l[0];
    *(us4*)(Op3 + base + 516) = *(us4*)&l[4];
}

// ---- site 0 (env0 = delta): env1 built by a cheap chain (fp32 exact) ----
__global__ void s0_g2(const float* __restrict__ state, const float* __restrict__ layer,
                      float* __restrict__ g2) {
    int t = blockIdx.x * 256 + threadIdx.x;          // 16384: [A][j][L]
    int A = t >> 8, j = (t >> 4) & 15, L = t & 15;
    float s = 0;
    for (int i = 0; i < 16; i++) s += state[i * 64 + A] * layer[(j * 16 + i) * 16 + L];
    g2[t] = s;
}
__global__ void s0_g3(const float* __restrict__ g2, const float* __restrict__ oper,
                      float* __restrict__ g3) {
    int t = blockIdx.x * 256 + threadIdx.x;          // 65536: [A][L][k][O]
    int A = t >> 10, L = (t >> 6) & 15, k = (t >> 2) & 15, O = t & 3;
    float s = 0;
    for (int j = 0; j < 16; j++) s += g2[A * 256 + j * 16 + L] * oper[(j * 16 + k) * 4 + O];
    g3[t] = s;
}
__global__ void s0_g4(const float* __restrict__ g3, const float* __restrict__ layer,
                      float* __restrict__ g4) {
    int t = blockIdx.x * 256 + threadIdx.x;          // 1048576: [A][L][O][s][M]
    int A = t >> 14, L = (t >> 10) & 15, O = (t >> 8) & 3, sp = (t >> 4) & 15, M = t & 15;
    float s = 0;
    for (int k = 0; k < 16; k++)
        s += g3[A * 1024 + L * 64 + k * 4 + O] * layer[(k * 16 + sp) * 16 + M];
    g4[t] = s;
}
__global__ void s0_env(const float* __restrict__ g4, const float* __restrict__ state,
                       float* __restrict__ env) {
    int t = blockIdx.x * 256 + threadIdx.x;          // 4194304: [A][L][O][M][B]
    int A = t >> 16, L = (t >> 12) & 15, O = (t >> 10) & 3, M = (t >> 6) & 15, B = t & 63;
    float s = 0;
    for (int sp = 0; sp < 16; sp++)
        s += g4[A * 16384 + L * 1024 + O * 256 + sp * 16 + M] * state[sp * 64 + B];
    env[t] = s;
}

// ---- site 7 chain (fp32) + fused dot ------------------------------------
__global__ void s7_c1(const float* __restrict__ state, const float* __restrict__ layer,
                      float* __restrict__ c1) {
    int t = blockIdx.x * 256 + threadIdx.x;          // 16384: [l][a][j]
    int l = t >> 10, a = (t >> 4) & 63, j = t & 15;
    float s = 0;
    for (int i = 0; i < 16; i++)
        s += state[7 * 65536 + (a * 16 + i) * 64] * layer[7 * 65536 + ((l * 16 + j) * 16 + i) * 16];
    c1[t] = s;
}
__global__ void s7_c2(const float* __restrict__ c1, const float* __restrict__ oper,
                      float* __restrict__ c2) {
    int t = blockIdx.x * 256 + threadIdx.x;          // 65536: [o][l][a][k]
    int o = t >> 14, l = (t >> 10) & 15, a = (t >> 4) & 63, k = t & 15;
    float s = 0;
    for (int j = 0; j < 16; j++)
        s += c1[l * 1024 + a * 16 + j] * oper[7 * 4096 + ((o * 16 + j) * 16 + k) * 4];
    c2[t] = s;
}
__global__ void s7_c3(const float* __restrict__ c2, const float* __restrict__ layer,
                      float* __restrict__ c3) {
    int t = blockIdx.x * 256 + threadIdx.x;          // 1048576: [m][o][l][a][s]
    int m = t >> 16, o = (t >> 14) & 3, l = (t >> 10) & 15, a = (t >> 4) & 63, sp = t & 15;
    float s = 0;
    for (int k = 0; k < 16; k++)
        s += c2[o * 16384 + l * 1024 + a * 16 + k] *
             layer[7 * 65536 + ((m * 16 + k) * 16 + sp) * 16];
    c3[t] = s;
}
__global__ void prep_sv(const float* __restrict__ state, float* __restrict__ sv) {
    int t = blockIdx.x * 256 + threadIdx.x;          // 1024: [b][sp]
    sv[t] = state[7 * 65536 + t * 64];
}
__global__ __launch_bounds__(256) void s7_fused(const float* __restrict__ env,
                                                const float* __restrict__ c3,
                                                const float* __restrict__ sv,
                                                float* __restrict__ out) {
    __shared__ float c3s[1024], svs[1024], red[256];
    int t = threadIdx.x;
    int n0 = blockIdx.x * 64;            // 1024 blocks; n=(l,o,m,b)
    int l = n0 >> 12, o = (n0 >> 10) & 3, m = (n0 >> 6) & 15;
    const float* c3b = c3 + m * 65536 + o * 16384 + l * 1024;   // [a][sp]
    for (int i = t; i < 1024; i += 256) { c3s[i] = c3b[i]; svs[i] = sv[i]; }
    __syncthreads();
    float s = 0;
    int b = t & 63, ag = t >> 6;
#pragma unroll
    for (int g = 0; g < 16; g++) {
        int a = ag * 16 + g;
        float e = env[(size_t)a * 65536 + n0 + b];
        float w = 0;
#pragma unroll
        for (int sp = 0; sp < 16; sp++) w += c3s[a * 16 + sp] * svs[b * 16 + sp];
        s += e * w;
    }
    red[t] = s; __syncthreads();
    for (int off = 128; off; off >>= 1) { if (t < off) red[t] += red[t + off]; __syncthreads(); }
    if (t == 0) atomicAdd(out, red[0]);
}

// ---- unified bf16x3 MFMA GEMM -------------------------------------------
// C[m,n] = sum_k Amat[k,m]*B[k,n]. Block = 4 waves, BN=64.
// WS=0: waves split m (M=256, MT=16), each wave 4mt x 4nt.
// WS=1: waves split n (M=64,  MT=4),  each wave 4mt x 1nt (16-n slice).
// BFMT=0: B = pre-split u32 plane [k/32][n][32]; BFMT=1: B = fp32 [k][n].
template <int KT, int MT, int WS, int BFMT, int SM>
__global__ __launch_bounds__(256) void gemm_u(const void* __restrict__ Bv,
                                              const unsigned short* __restrict__ Ap,
                                              float* __restrict__ Cf,
                                              unsigned* __restrict__ Cu,
                                              int Nfull, int A0) {
    constexpr int NT = (WS == 0) ? 4 : 1;
    __shared__ unsigned short Bs_h[64 * 40];
    __shared__ unsigned short Bs_l[64 * 40];
    const int tid = threadIdx.x, lane = tid & 63, wave = tid >> 6;
    const int quad = lane >> 4, lr = lane & 15;
    const int n0 = blockIdx.x * 64;

    f32x4 acc[4][NT];
#pragma unroll
    for (int i = 0; i < 4; i++)
#pragma unroll
        for (int j = 0; j < NT; j++)
#pragma unroll
            for (int r = 0; r < 4; r++) acc[i][j][r] = 0.0f;

    uint4 ur[2];
    float4 fr[2];

    auto load_tile = [&](int k0) {
        if constexpr (BFMT == 0) {
            const unsigned* src = (const unsigned*)Bv +
                                  (size_t)k0 * ((size_t)Nfull * 32) + (size_t)n0 * 32;
#pragma unroll
            for (int v = 0; v < 2; v++) ur[v] = ((const uint4*)src)[v * 256 + tid];
        } else {
            const float* Bf = (const float*)Bv;
#pragma unroll
            for (int v = 0; v < 2; v++) {
                int e = v * 256 + tid;
                int kk = e >> 4, nn4 = (e & 15) * 4;
                fr[v] = *(const float4*)(Bf + (size_t)(k0 * 32 + kk) * Nfull + n0 + nn4);
            }
        }
    };
    auto store_tile = [&]() {
        if constexpr (BFMT == 0) {
#pragma unroll
            for (int v = 0; v < 2; v++) {
                int e = v * 256 + tid;
                int nl = e >> 3, k4 = (e & 7) * 4;
                us4 hv, lv;
                hv[0] = (unsigned short)ur[v].x; lv[0] = (unsigned short)(ur[v].x >> 16);
                hv[1] = (unsigned short)ur[v].y; lv[1] = (unsigned short)(ur[v].y >> 16);
                hv[2] = (unsigned short)ur[v].z; lv[2] = (unsigned short)(ur[v].z >> 16);
                hv[3] = (unsigned short)ur[v].w; lv[3] = (unsigned short)(ur[v].w >> 16);
                *(us4*)(&Bs_h[nl * 40 + k4]) = hv;
                *(us4*)(&Bs_l[nl * 40 + k4]) = lv;
            }
        } else {
#pragma unroll
            for (int v = 0; v < 2; v++) {
                int e = v * 256 + tid;
                int kk = e >> 4, nn4 = (e & 15) * 4;
                float ff[4] = {fr[v].x, fr[v].y, fr[v].z, fr[v].w};
#pragma unroll
                for (int i = 0; i < 4; i++) {
                    unsigned s = split2(ff[i]);
                    Bs_h[(nn4 + i) * 40 + kk] = (unsigned short)s;
                    Bs_l[(nn4 + i) * 40 + kk] = (unsigned short)(s >> 16);
                }
            }
        }
    };

    load_tile(0);
    store_tile();
    for (int k0 = 0; k0 < KT; k0++) {
        __syncthreads();                       // tile k0 visible
        if (k0 + 1 < KT) load_tile(k0 + 1);    // overlap next load with MFMA
        bf16x8 ah[4], al[4];
#pragma unroll
        for (int mt = 0; mt < 4; mt++) {
            int gmt = (WS == 0) ? (wave * 4 + mt) : mt;
            const unsigned short* ap = Ap + ((size_t)(k0 * MT + gmt) * 2) * 512 + lane * 8;
            ah[mt] = *(const bf16x8*)ap;
            al[mt] = *(const bf16x8*)(ap + 512);
        }
#pragma unroll
        for (int nt = 0; nt < NT; nt++) {
            int nl = (WS == 0) ? (nt * 16 + lr) : (wave * 16 + lr);
            bf16x8 bh = *(bf16x8*)(&Bs_h[nl * 40 + quad * 8]);
            bf16x8 bl = *(bf16x8*)(&Bs_l[nl * 40 + quad * 8]);
#pragma unroll
            for (int mt = 0; mt < 4; mt++) {
                acc[mt][nt] = __builtin_amdgcn_mfma_f32_16x16x32_bf16(ah[mt], bh, acc[mt][nt], 0, 0, 0);
                acc[mt][nt] = __builtin_amdgcn_mfma_f32_16x16x32_bf16(ah[mt], bl, acc[mt][nt], 0, 0, 0);
                acc[mt][nt] = __builtin_amdgcn_mfma_f32_16x16x32_bf16(al[mt], bh, acc[mt][nt], 0, 0, 0);
            }
        }
        __syncthreads();                       // done reading tile k0
        if (k0 + 1 < KT) store_tile();
    }

#pragma unroll
    for (int mt = 0; mt < 4; mt++) {
        int gmt = (WS == 0) ? (wave * 4 + mt) : mt;
#pragma unroll
        for (int nt = 0; nt < NT; nt++) {
            int n = n0 + ((WS == 0) ? nt * 16 : wave * 16) + lr;
#pragma unroll
            for (int r = 0; r < 4; r++) {
                int m = gmt * 16 + quad * 4 + r;
                float val = acc[mt][nt][r];
                if constexpr (SM == 1) {
                    // n=(l,o,m2,b) env col; m=(i,a4) -> t1 plane
                    int kn = (n >> 12) * 16 + (m >> 4);
                    int nn = ((n >> 10) & 3) * 16384 + ((n >> 6) & 15) * 1024 +
                             (n & 63) * 16 + (m & 15);
                    Cu[(size_t)(kn >> 5) * 2097152 + (size_t)nn * 32 + (kn & 31)] = split2(val);
                } else if constexpr (SM == 2) {
                    // n=(o,m2,b,a4) t1 col; m=(j,L) -> t2 fp32 [(o,j)][L,m2,b,a4]
                    Cf[(size_t)((n >> 14) * 16 + (m >> 4)) * 262144 +
                       (m & 15) * 16384 + (n & 16383)] = val;
                } else if constexpr (SM == 3) {
                    // n=(L,m2,b,a4) t2 col; m=(k2,O2) -> t3 plane
                    int kn = ((n >> 10) & 15) * 16 + (m >> 2);
                    int nn = (m & 3) * 16384 + ((n >> 4) & 63) * 256 +
                             ((n >> 14) << 4) + (n & 15);
                    Cu[(size_t)(kn >> 5) * 2097152 + (size_t)nn * 32 + (kn & 31)] = split2(val);
                } else if constexpr (SM == 4) {
                    // n=(O2,b,L,a4) t3 col; m=(s,M2) -> t4 fp32 [(b,s)][M2,L,O2,a4]
                    Cf[(size_t)(((n >> 8) & 63) * 16 + (m >> 4)) * 16384 +
                       (m & 15) * 1024 + ((n >> 4) & 15) * 64 +
                       ((n >> 14) << 4) + (n & 15)] = val;
                } else {
                    // n=(M2,L,O2,a4) t4 col; m=B' -> env'[A0+a4][L,O2,M2,B'] fp32
                    Cf[(size_t)(A0 + (n & 15)) * 65536 + ((n >> 6) & 15) * 4096 +
                       ((n >> 4) & 3) * 1024 + (n >> 10) * 64 + m] = val;
                }
            }
        }
    }
}

extern "C" void kernel_launch(void* const* d_in, const int* in_sizes, int n_in,
                              void* d_out, int out_size, void* d_ws, size_t ws_size,
                              hipStream_t stream) {
    const float* state = (const float*)d_in[0];   // [8,64,16,64]
    const float* layer = (const float*)d_in[1];   // [1,8,16,16,16,16]
    const float* oper  = (const float*)d_in[2];   // [8,4,16,16,4]
    float* out = (float*)d_out;

    // ws: F(16.8M f32) | P(16.8M u32) | envA | envB | Ap2|Ap4|Sp1|Sp5|Op3 | sv
    const size_t need = (16777216ull + 16777216ull + 2 * 4194304ull) * 4ull +
                        (4 * 1048576ull + 65536ull) * 2ull + 4096ull;
    if (ws_size < need) {
        write_diag_kernel<<<1, 64, 0, stream>>>(out, (float)ws_size);
        return;
    }
    float* F    = (float*)d_ws;
    unsigned* P = (unsigned*)(F + 16777216);
    float* envA = (float*)(P + 16777216);
    float* envB = envA + 4194304;
    unsigned short* Ap2 = (unsigned short*)(envB + 4194304);
    unsigned short* Ap4 = Ap2 + 1048576;
    unsigned short* Sp1 = Ap4 + 1048576;
    unsigned short* Sp5 = Sp1 + 1048576;
    unsigned short* Op3 = Sp5 + 1048576;
    float* sv = (float*)(Op3 + 65536);
    float* SCR = F;   // boundary-chain fp32 scratch (F free at those times)

    prep_apack<<<256, 256, 0, stream>>>(layer, Ap2, Ap4);
    prep_spack1<<<256, 256, 0, stream>>>(state, Sp1);
    prep_spack5<<<256, 256, 0, stream>>>(state, Sp5);
    prep_opack3<<<16, 256, 0, stream>>>(oper, Op3);
    prep_sv<<<4, 256, 0, stream>>>(state, sv);

    // site 0 -> envB (exact fp32)
    s0_g2<<<64, 256, 0, stream>>>(state, layer, SCR);
    s0_g3<<<256, 256, 0, stream>>>(SCR, oper, SCR + 16384);
    s0_g4<<<4096, 256, 0, stream>>>(SCR + 16384, layer, SCR + 81920);
    s0_env<<<16384, 256, 0, stream>>>(SCR + 81920, state, envB);

    for (int q = 1; q < 7; q++) {
        float* ein  = (q & 1) ? envB : envA;
        float* eout = (q & 1) ? envA : envB;
        for (int c = 0; c < 4; c++) {
            // G1: env (fp32) x Sp1 -> t1 plane
            gemm_u<2, 16, 0, 1, 1><<<1024, 256, 0, stream>>>(
                ein, Sp1 + (size_t)(q * 4 + c) * 32768, nullptr, P, 65536, 0);
            // G2: t1 plane x Ap2 -> t2 fp32
            gemm_u<8, 16, 0, 0, 2><<<1024, 256, 0, stream>>>(
                P, Ap2 + (size_t)q * 131072, F, nullptr, 65536, 0);
            // G3: t2 fp32 x Op3 -> t3 plane
            gemm_u<2, 4, 1, 1, 3><<<4096, 256, 0, stream>>>(
                F, Op3 + (size_t)q * 8192, nullptr, P, 262144, 0);
            // G4: t3 plane x Ap4 -> t4 fp32
            gemm_u<8, 16, 0, 0, 4><<<1024, 256, 0, stream>>>(
                P, Ap4 + (size_t)q * 131072, F, nullptr, 65536, 0);
            // G5: t4 fp32 x Sp5 -> env' fp32 (A-slice c)
            gemm_u<32, 4, 1, 1, 5><<<256, 256, 0, stream>>>(
                F, Sp5 + (size_t)q * 131072, eout, nullptr, 16384, c * 16);
        }
    }

    // site 7: out = <env7 (fp32, in envB), w> with w built on the fly
    s7_c1<<<64, 256, 0, stream>>>(state, layer, SCR);
    s7_c2<<<256, 256, 0, stream>>>(SCR, oper, SCR + 16384);
    s7_c3<<<4096, 256, 0, stream>>>(SCR + 16384, layer, SCR + 81920);
    zero_out<<<1, 64, 0, stream>>>(out);
    s7_fused<<<1024, 256, 0, stream>>>(envB, SCR + 81920, sv, out);
}

// Round 7
// 3443.934 us; speedup vs baseline: 3.6161x; 1.5295x over previous
//
#include <hip/hip_runtime.h>

// ---------------------------------------------------------------------------
// <psi|U^dag O U|psi>, NQ=8, r=64 d=16 rl=16 ro=4.
// R7: all intermediates n-INNERMOST so every epilogue store is dense (R6's
// k-inner split-planes caused 4x HBM write amplification: partial 128B lines
// split across blocks/XCDs). Transposing hops (t4, env) stored column-major
// [n][k] so the WRITER is dense; consumers stage row-strips (LLC-absorbed).
// Formats:
//   env  fp32 [n=(l,o,m2,b)·65536][a·64]            (col-major, G5 dense)
//   t1   u32  [k=(l,i)·256][n=(o,m2,a4,b)·65536]    (hi|lo<<16 split pair)
//   t2   fp32 [k=(o,j)·64][n=(L,m2,a4,b)·262144]
//   t3   u32  [k=(m2,k2)·256][n=(O2,L,a4,b)·65536]
//   t4   fp32 [n=(M2,L,O2,a4)·16384][k=(s,b)·1024]  (col-major, G4 dense)
// A-packs in MFMA fragment order (unchanged except Sp5 k-order = (s,b)).
// Boundary sites 0/7: cheap fp32 rank-structured chains.
// ---------------------------------------------------------------------------

typedef __attribute__((ext_vector_type(8))) short bf16x8;
typedef __attribute__((ext_vector_type(4))) float f32x4;
typedef __attribute__((ext_vector_type(4))) unsigned short us4;

static __device__ __forceinline__ unsigned short f2bf(float x) {
    union { float f; unsigned u; } a; a.f = x;
    return (unsigned short)((a.u + 0x7FFF + ((a.u >> 16) & 1)) >> 16);
}
static __device__ __forceinline__ float bf2f(unsigned short h) {
    union { unsigned u; float f; } a; a.u = (unsigned)h << 16; return a.f;
}
static __device__ __forceinline__ unsigned split2(float x) {
    unsigned short h = f2bf(x);
    unsigned short l = f2bf(x - bf2f(h));
    return (unsigned)h | ((unsigned)l << 16);
}

__global__ void write_diag_kernel(float* out, float v) {
    if (threadIdx.x == 0 && blockIdx.x == 0) out[0] = v;
}
__global__ void zero_out(float* o) {
    if (threadIdx.x == 0 && blockIdx.x == 0) o[0] = 0.0f;
}

// ---- A-operand fragment packs -------------------------------------------
// Pack layout: [(k0*MT+mt)*2+hl][lane(64)][8]; frag k = k0*32+quad*8+j,
// m = mt*16 + (lane&15).

// G2 (Ud, k=(l,i), m=(j,L)) / G4 (U, k=(m2,k2), m=(s,M2)); MT=16, KT=8
__global__ void prep_apack(const float* __restrict__ layer,
                           unsigned short* __restrict__ Ap2,
                           unsigned short* __restrict__ Ap4) {
    int idx = blockIdx.x * 256 + threadIdx.x;   // 65536
    int q = idx >> 13, k0 = (idx >> 10) & 7, mt = (idx >> 6) & 15, lane = idx & 63;
    int quad = lane >> 4, r = lane & 15;
    unsigned short h2[8], l2[8], h4[8], l4[8];
#pragma unroll
    for (int j = 0; j < 8; j++) {
        int k = k0 * 32 + quad * 8 + j;
        int m = mt * 16 + r;
        float v2 = layer[(size_t)q * 65536 +
                         (size_t)((((k >> 4) * 16 + (m >> 4)) * 16 + (k & 15)) * 16 + (m & 15))];
        float v4 = layer[(size_t)q * 65536 +
                         (size_t)((((k >> 4) * 16 + (k & 15)) * 16 + (m >> 4)) * 16 + (m & 15))];
        h2[j] = f2bf(v2); l2[j] = f2bf(v2 - bf2f(h2[j]));
        h4[j] = f2bf(v4); l4[j] = f2bf(v4 - bf2f(h4[j]));
    }
    size_t base = ((size_t)((q * 8 + k0) * 16 + mt) * 2) * 512 + lane * 8;
    *(us4*)(Ap2 + base)       = *(us4*)&h2[0];
    *(us4*)(Ap2 + base + 4)   = *(us4*)&h2[4];
    *(us4*)(Ap2 + base + 512) = *(us4*)&l2[0];
    *(us4*)(Ap2 + base + 516) = *(us4*)&l2[4];
    *(us4*)(Ap4 + base)       = *(us4*)&h4[0];
    *(us4*)(Ap4 + base + 4)   = *(us4*)&h4[4];
    *(us4*)(Ap4 + base + 512) = *(us4*)&l4[0];
    *(us4*)(Ap4 + base + 516) = *(us4*)&l4[4];
}

// G1 (S as A): Amat[k=a][m=(i,a4)] = state[q][a][i][c*16+a4]; MT=16, KT=2
__global__ void prep_spack1(const float* __restrict__ state,
                            unsigned short* __restrict__ Sp1) {
    int idx = blockIdx.x * 256 + threadIdx.x;   // 65536
    int q = idx >> 13, c = (idx >> 11) & 3, k0 = (idx >> 10) & 1,
        mt = (idx >> 6) & 15, lane = idx & 63;
    int quad = lane >> 4, lr = lane & 15;
    unsigned short h[8], l[8];
#pragma unroll
    for (int j = 0; j < 8; j++) {
        int k = k0 * 32 + quad * 8 + j;
        float v = state[(size_t)q * 65536 + (size_t)(k * 16 + mt) * 64 + c * 16 + lr];
        h[j] = f2bf(v); l[j] = f2bf(v - bf2f(h[j]));
    }
    size_t base = (size_t)(q * 4 + c) * 32768 + ((size_t)(k0 * 16 + mt) * 2) * 512 + lane * 8;
    *(us4*)(Sp1 + base)       = *(us4*)&h[0];
    *(us4*)(Sp1 + base + 4)   = *(us4*)&h[4];
    *(us4*)(Sp1 + base + 512) = *(us4*)&l[0];
    *(us4*)(Sp1 + base + 516) = *(us4*)&l[4];
}

// G5 (S as A): Amat[k=(s,b)=s*64+b][m=B'] = state[q][b][s][B']; MT=4, KT=32
__global__ void prep_spack5(const float* __restrict__ state,
                            unsigned short* __restrict__ Sp5) {
    int idx = blockIdx.x * 256 + threadIdx.x;   // 65536
    int q = idx >> 13, k0 = (idx >> 8) & 31, mt = (idx >> 6) & 3, lane = idx & 63;
    int quad = lane >> 4, lr = lane & 15;
    unsigned short h[8], l[8];
#pragma unroll
    for (int j = 0; j < 8; j++) {
        int k = k0 * 32 + quad * 8 + j;   // k = s*64+b
        int s = k >> 6, b = k & 63;
        float v = state[(size_t)q * 65536 + (size_t)(b * 16 + s) * 64 + mt * 16 + lr];
        h[j] = f2bf(v); l[j] = f2bf(v - bf2f(h[j]));
    }
    size_t base = (size_t)q * 131072 + ((size_t)(k0 * 4 + mt) * 2) * 512 + lane * 8;
    *(us4*)(Sp5 + base)       = *(us4*)&h[0];
    *(us4*)(Sp5 + base + 4)   = *(us4*)&h[4];
    *(us4*)(Sp5 + base + 512) = *(us4*)&l[0];
    *(us4*)(Sp5 + base + 516) = *(us4*)&l[4];
}

// G3 (O as A): Amat[k=(o,j2)][m=(k2,O2)] = oper[q][o][j2][k2][O2]; MT=4, KT=2
__global__ void prep_opack3(const float* __restrict__ oper,
                            unsigned short* __restrict__ Op3) {
    int idx = blockIdx.x * 256 + threadIdx.x;   // 4096
    int q = idx >> 9, k0 = (idx >> 8) & 1, mt = (idx >> 6) & 3, lane = idx & 63;
    int quad = lane >> 4, lr = lane & 15;
    unsigned short h[8], l[8];
#pragma unroll
    for (int j = 0; j < 8; j++) {
        int k = k0 * 32 + quad * 8 + j;
        int m = mt * 16 + lr;
        float v = oper[(size_t)q * 4096 + (size_t)(k * 16 + (m >> 2)) * 4 + (m & 3)];
        h[j] = f2bf(v); l[j] = f2bf(v - bf2f(h[j]));
    }
    size_t base = (size_t)q * 8192 + ((size_t)(k0 * 4 + mt) * 2) * 512 + lane * 8;
    *(us4*)(Op3 + base)       = *(us4*)&h[0];
    *(us4*)(Op3 + base + 4)   = *(us4*)&h[4];
    *(us4*)(Op3 + base + 512) = *(us4*)&l[0];
    *(us4*)(Op3 + base + 516) = *(us4*)&l[4];
}

// ---- site 0 (env0 = delta): env1 built by a cheap chain (fp32 exact) ----
__global__ void s0_g2(const float* __restrict__ state, const float* __restrict__ layer,
                      float* __restrict__ g2) {
    int t = blockIdx.x * 256 + threadIdx.x;          // 16384: [A][j][L]
    int A = t >> 8, j = (t >> 4) & 15, L = t & 15;
    float s = 0;
    for (int i = 0; i < 16; i++) s += state[i * 64 + A] * layer[(j * 16 + i) * 16 + L];
    g2[t] = s;
}
__global__ void s0_g3(const float* __restrict__ g2, const float* __restrict__ oper,
                      float* __restrict__ g3) {
    int t = blockIdx.x * 256 + threadIdx.x;          // 65536: [A][L][k][O]
    int A = t >> 10, L = (t >> 6) & 15, k = (t >> 2) & 15, O = t & 3;
    float s = 0;
    for (int j = 0; j < 16; j++) s += g2[A * 256 + j * 16 + L] * oper[(j * 16 + k) * 4 + O];
    g3[t] = s;
}
__global__ void s0_g4(const float* __restrict__ g3, const float* __restrict__ layer,
                      float* __restrict__ g4) {
    int t = blockIdx.x * 256 + threadIdx.x;          // 1048576: [A][L][O][s][M]
    int A = t >> 14, L = (t >> 10) & 15, O = (t >> 8) & 3, sp = (t >> 4) & 15, M = t & 15;
    float s = 0;
    for (int k = 0; k < 16; k++)
        s += g3[A * 1024 + L * 64 + k * 4 + O] * layer[(k * 16 + sp) * 16 + M];
    g4[t] = s;
}
// env col-major: env[(L*4096+O*1024+M*64+B)*64 + A]; lanes -> A (dense)
__global__ void s0_env(const float* __restrict__ g4, const float* __restrict__ state,
                       float* __restrict__ env) {
    int t = blockIdx.x * 256 + threadIdx.x;          // 4194304: [L][O][M][B][A]
    int A = t & 63, B = (t >> 6) & 63, M = (t >> 12) & 15, O = (t >> 16) & 3, L = t >> 18;
    float s = 0;
    for (int sp = 0; sp < 16; sp++)
        s += g4[A * 16384 + L * 1024 + O * 256 + sp * 16 + M] * state[sp * 64 + B];
    env[t] = s;
}

// ---- site 7 chain (fp32) + fused dot ------------------------------------
__global__ void s7_c1(const float* __restrict__ state, const float* __restrict__ layer,
                      float* __restrict__ c1) {
    int t = blockIdx.x * 256 + threadIdx.x;          // 16384: [l][a][j]
    int l = t >> 10, a = (t >> 4) & 63, j = t & 15;
    float s = 0;
    for (int i = 0; i < 16; i++)
        s += state[7 * 65536 + (a * 16 + i) * 64] * layer[7 * 65536 + ((l * 16 + j) * 16 + i) * 16];
    c1[t] = s;
}
__global__ void s7_c2(const float* __restrict__ c1, const float* __restrict__ oper,
                      float* __restrict__ c2) {
    int t = blockIdx.x * 256 + threadIdx.x;          // 65536: [o][l][a][k]
    int o = t >> 14, l = (t >> 10) & 15, a = (t >> 4) & 63, k = t & 15;
    float s = 0;
    for (int j = 0; j < 16; j++)
        s += c1[l * 1024 + a * 16 + j] * oper[7 * 4096 + ((o * 16 + j) * 16 + k) * 4];
    c2[t] = s;
}
__global__ void s7_c3(const float* __restrict__ c2, const float* __restrict__ layer,
                      float* __restrict__ c3) {
    int t = blockIdx.x * 256 + threadIdx.x;          // 1048576: [m][o][l][a][s]
    int m = t >> 16, o = (t >> 14) & 3, l = (t >> 10) & 15, a = (t >> 4) & 63, sp = t & 15;
    float s = 0;
    for (int k = 0; k < 16; k++)
        s += c2[o * 16384 + l * 1024 + a * 16 + k] *
             layer[7 * 65536 + ((m * 16 + k) * 16 + sp) * 16];
    c3[t] = s;
}
__global__ void prep_sv(const float* __restrict__ state, float* __restrict__ sv) {
    int t = blockIdx.x * 256 + threadIdx.x;          // 1024: [b][sp]
    sv[t] = state[7 * 65536 + t * 64];
}
__global__ __launch_bounds__(256) void s7_fused(const float* __restrict__ env,
                                                const float* __restrict__ c3,
                                                const float* __restrict__ sv,
                                                float* __restrict__ out) {
    __shared__ float c3s[1024], svs[1024], red[256];
    int t = threadIdx.x;
    int n0 = blockIdx.x * 64;            // 1024 blocks; n=(l,o,m,b)
    int l = n0 >> 12, o = (n0 >> 10) & 3, m = (n0 >> 6) & 15;
    const float* c3b = c3 + m * 65536 + o * 16384 + l * 1024;   // [a][sp]
    for (int i = t; i < 1024; i += 256) { c3s[i] = c3b[i]; svs[i] = sv[i]; }
    __syncthreads();
    float s = 0;
    int b = t & 63, ag = t >> 6;
#pragma unroll
    for (int g = 0; g < 16; g++) {
        int a = ag * 16 + g;
        float e = env[(size_t)(n0 + b) * 64 + a];   // env col-major [n][a]
        float w = 0;
#pragma unroll
        for (int sp = 0; sp < 16; sp++) w += c3s[a * 16 + sp] * svs[b * 16 + sp];
        s += e * w;
    }
    red[t] = s; __syncthreads();
    for (int off = 128; off; off >>= 1) { if (t < off) red[t] += red[t + off]; __syncthreads(); }
    if (t == 0) atomicAdd(out, red[0]);
}

// ---- unified bf16x3 MFMA GEMM -------------------------------------------
// C[m,n] = sum_k Amat[k,m]*B[k,n]. Block = 4 waves, BN=64.
// WS=0: waves split m (M=256, MT=16); WS=1: waves split n (M=64, MT=4).
// BFMT=0: B u32 split-pair [k][n]; BFMT=1: B fp32 [k][n];
// BFMT=2: B fp32 col-major [n][KLEN] (transposed consumer).
template <int KT, int MT, int WS, int BFMT, int KLEN, int SM>
__global__ __launch_bounds__(256) void gemm_u(const void* __restrict__ Bv,
                                              const unsigned short* __restrict__ Ap,
                                              float* __restrict__ Cf,
                                              unsigned* __restrict__ Cu,
                                              int Nfull, int A0) {
    constexpr int NT = (WS == 0) ? 4 : 1;
    __shared__ unsigned short Bs_h[64 * 40];
    __shared__ unsigned short Bs_l[64 * 40];
    const int tid = threadIdx.x, lane = tid & 63, wave = tid >> 6;
    const int quad = lane >> 4, lr = lane & 15;
    const int n0 = blockIdx.x * 64;
    const int snn = tid & 63, skg = tid >> 6;   // staging coords (BFMT 0/1)

    f32x4 acc[4][NT];
#pragma unroll
    for (int i = 0; i < 4; i++)
#pragma unroll
        for (int j = 0; j < NT; j++)
#pragma unroll
            for (int r = 0; r < 4; r++) acc[i][j][r] = 0.0f;

    unsigned ub[2][4];
    float    fb[2][4];
    float4   f4b[2];

    auto load_tile = [&](int k0) {
        if constexpr (BFMT == 0) {
            const unsigned* Bp = (const unsigned*)Bv;
#pragma unroll
            for (int v = 0; v < 2; v++)
#pragma unroll
                for (int i = 0; i < 4; i++) {
                    int kk = (v * 4 + skg) * 4 + i;
                    ub[v][i] = Bp[(size_t)(k0 * 32 + kk) * Nfull + n0 + snn];
                }
        } else if constexpr (BFMT == 1) {
            const float* Bf = (const float*)Bv;
#pragma unroll
            for (int v = 0; v < 2; v++)
#pragma unroll
                for (int i = 0; i < 4; i++) {
                    int kk = (v * 4 + skg) * 4 + i;
                    fb[v][i] = Bf[(size_t)(k0 * 32 + kk) * Nfull + n0 + snn];
                }
        } else {
            const float* Bf = (const float*)Bv;
#pragma unroll
            for (int v = 0; v < 2; v++) {
                int e = v * 256 + tid;
                int n2 = e >> 3, k4 = e & 7;
                f4b[v] = *(const float4*)(Bf + (size_t)(n0 + n2) * KLEN + k0 * 32 + k4 * 4);
            }
        }
    };
    auto store_tile = [&]() {
        if constexpr (BFMT == 0) {
#pragma unroll
            for (int v = 0; v < 2; v++) {
                us4 hv, lv;
#pragma unroll
                for (int i = 0; i < 4; i++) {
                    hv[i] = (unsigned short)ub[v][i];
                    lv[i] = (unsigned short)(ub[v][i] >> 16);
                }
                int base = snn * 40 + (v * 4 + skg) * 4;
                *(us4*)(&Bs_h[base]) = hv;
                *(us4*)(&Bs_l[base]) = lv;
            }
        } else if constexpr (BFMT == 1) {
#pragma unroll
            for (int v = 0; v < 2; v++) {
                us4 hv, lv;
#pragma unroll
                for (int i = 0; i < 4; i++) {
                    unsigned s = split2(fb[v][i]);
                    hv[i] = (unsigned short)s;
                    lv[i] = (unsigned short)(s >> 16);
                }
                int base = snn * 40 + (v * 4 + skg) * 4;
                *(us4*)(&Bs_h[base]) = hv;
                *(us4*)(&Bs_l[base]) = lv;
            }
        } else {
#pragma unroll
            for (int v = 0; v < 2; v++) {
                int e = v * 256 + tid;
                int n2 = e >> 3, k4 = e & 7;
                float ff[4] = {f4b[v].x, f4b[v].y, f4b[v].z, f4b[v].w};
                us4 hv, lv;
#pragma unroll
                for (int i = 0; i < 4; i++) {
                    unsigned s = split2(ff[i]);
                    hv[i] = (unsigned short)s;
                    lv[i] = (unsigned short)(s >> 16);
                }
                *(us4*)(&Bs_h[n2 * 40 + k4 * 4]) = hv;
                *(us4*)(&Bs_l[n2 * 40 + k4 * 4]) = lv;
            }
        }
    };

    load_tile(0);
    store_tile();
    for (int k0 = 0; k0 < KT; k0++) {
        __syncthreads();                       // tile k0 visible
        if (k0 + 1 < KT) load_tile(k0 + 1);    // overlap next load with MFMA
        bf16x8 ah[4], al[4];
#pragma unroll
        for (int mt = 0; mt < 4; mt++) {
            int gmt = (WS == 0) ? (wave * 4 + mt) : mt;
            const unsigned short* ap = Ap + ((size_t)(k0 * MT + gmt) * 2) * 512 + lane * 8;
            ah[mt] = *(const bf16x8*)ap;
            al[mt] = *(const bf16x8*)(ap + 512);
        }
#pragma unroll
        for (int nt = 0; nt < NT; nt++) {
            int nl = (WS == 0) ? (nt * 16 + lr) : (wave * 16 + lr);
            bf16x8 bh = *(bf16x8*)(&Bs_h[nl * 40 + quad * 8]);
            bf16x8 bl = *(bf16x8*)(&Bs_l[nl * 40 + quad * 8]);
#pragma unroll
            for (int mt = 0; mt < 4; mt++) {
                acc[mt][nt] = __builtin_amdgcn_mfma_f32_16x16x32_bf16(ah[mt], bh, acc[mt][nt], 0, 0, 0);
                acc[mt][nt] = __builtin_amdgcn_mfma_f32_16x16x32_bf16(ah[mt], bl, acc[mt][nt], 0, 0, 0);
                acc[mt][nt] = __builtin_amdgcn_mfma_f32_16x16x32_bf16(al[mt], bh, acc[mt][nt], 0, 0, 0);
            }
        }
        __syncthreads();                       // done reading tile k0
        if (k0 + 1 < KT) store_tile();
    }

#pragma unroll
    for (int mt = 0; mt < 4; mt++) {
        int gmt = (WS == 0) ? (wave * 4 + mt) : mt;
#pragma unroll
        for (int nt = 0; nt < NT; nt++) {
            int n = n0 + ((WS == 0) ? nt * 16 : wave * 16) + lr;
#pragma unroll
            for (int r = 0; r < 4; r++) {
                int m = gmt * 16 + quad * 4 + r;
                float val = acc[mt][nt][r];
                if constexpr (SM == 1) {
                    // n = env col (l,o,m2,b); m=(i,a4) -> t1[(l,i)][o,m2,a4,b]
                    int l = n >> 12, o = (n >> 10) & 3, m2 = (n >> 6) & 15, b = n & 63;
                    Cu[(size_t)(l * 16 + (m >> 4)) * 65536 +
                       o * 16384 + m2 * 1024 + (m & 15) * 64 + b] = split2(val);
                } else if constexpr (SM == 2) {
                    // n = t1 col (o,m2,a4,b); m=(j,L) -> t2[(o,j)][L,m2,a4,b]
                    Cf[(size_t)((n >> 14) * 16 + (m >> 4)) * 262144 +
                       (m & 15) * 16384 + (n & 16383)] = val;
                } else if constexpr (SM == 3) {
                    // n = t2 col (L,m2,a4,b); m=(k2,O2) -> t3[(m2,k2)][O2,L,a4,b]
                    int L = n >> 14, m2 = (n >> 10) & 15;
                    Cu[(size_t)(m2 * 16 + (m >> 2)) * 65536 +
                       (m & 3) * 16384 + L * 1024 + (n & 1023)] = split2(val);
                } else if constexpr (SM == 4) {
                    // n = t3 col (O2,L,a4,b); m=(s,M2)
                    //  -> t4'[col=(M2,L,O2,a4)][k=s*64+b]  (col-major)
                    int O2 = n >> 14, L = (n >> 10) & 15, a4 = (n >> 6) & 15, b = n & 63;
                    Cf[(size_t)((m & 15) * 1024 + L * 64 + O2 * 16 + a4) * 1024 +
                       (m >> 4) * 64 + b] = val;
                } else {
                    // n = t4' col (M2,L,O2,a4); m=B' -> env'[(L,O2,M2,B')][A0+a4]
                    int M2 = n >> 10, L = (n >> 6) & 15, O2 = (n >> 4) & 3, a4 = n & 15;
                    Cf[(size_t)(L * 4096 + O2 * 1024 + M2 * 64 + m) * 64 + A0 + a4] = val;
                }
            }
        }
    }
}

extern "C" void kernel_launch(void* const* d_in, const int* in_sizes, int n_in,
                              void* d_out, int out_size, void* d_ws, size_t ws_size,
                              hipStream_t stream) {
    const float* state = (const float*)d_in[0];   // [8,64,16,64]
    const float* layer = (const float*)d_in[1];   // [1,8,16,16,16,16]
    const float* oper  = (const float*)d_in[2];   // [8,4,16,16,4]
    float* out = (float*)d_out;

    // ws: F(16.8M f32) | P(16.8M u32) | envA | envB | Ap2|Ap4|Sp1|Sp5|Op3 | sv
    const size_t need = (16777216ull + 16777216ull + 2 * 4194304ull) * 4ull +
                        (4 * 1048576ull + 65536ull) * 2ull + 4096ull;
    if (ws_size < need) {
        write_diag_kernel<<<1, 64, 0, stream>>>(out, (float)ws_size);
        return;
    }
    float* F    = (float*)d_ws;
    unsigned* P = (unsigned*)(F + 16777216);
    float* envA = (float*)(P + 16777216);
    float* envB = envA + 4194304;
    unsigned short* Ap2 = (unsigned short*)(envB + 4194304);
    unsigned short* Ap4 = Ap2 + 1048576;
    unsigned short* Sp1 = Ap4 + 1048576;
    unsigned short* Sp5 = Sp1 + 1048576;
    unsigned short* Op3 = Sp5 + 1048576;
    float* sv = (float*)(Op3 + 65536);
    float* SCR = F;   // boundary-chain fp32 scratch (F free at those times)

    prep_apack<<<256, 256, 0, stream>>>(layer, Ap2, Ap4);
    prep_spack1<<<256, 256, 0, stream>>>(state, Sp1);
    prep_spack5<<<256, 256, 0, stream>>>(state, Sp5);
    prep_opack3<<<16, 256, 0, stream>>>(oper, Op3);
    prep_sv<<<4, 256, 0, stream>>>(state, sv);

    // site 0 -> envB (exact fp32), env stored col-major [n][a]
    s0_g2<<<64, 256, 0, stream>>>(state, layer, SCR);
    s0_g3<<<256, 256, 0, stream>>>(SCR, oper, SCR + 16384);
    s0_g4<<<4096, 256, 0, stream>>>(SCR + 16384, layer, SCR + 81920);
    s0_env<<<16384, 256, 0, stream>>>(SCR + 81920, state, envB);

    for (int q = 1; q < 7; q++) {
        float* ein  = (q & 1) ? envB : envA;
        float* eout = (q & 1) ? envA : envB;
        for (int c = 0; c < 4; c++) {
            // G1: env [n][64] (BFMT=2) x Sp1 -> t1 u32 [k][n]
            gemm_u<2, 16, 0, 2, 64, 1><<<1024, 256, 0, stream>>>(
                ein, Sp1 + (size_t)(q * 4 + c) * 32768, nullptr, P, 65536, 0);
            // G2: t1 u32 [k][n] (BFMT=0) x Ap2 -> t2 fp32 [k][n]
            gemm_u<8, 16, 0, 0, 0, 2><<<1024, 256, 0, stream>>>(
                P, Ap2 + (size_t)q * 131072, F, nullptr, 65536, 0);
            // G3: t2 fp32 [k][n] (BFMT=1) x Op3 -> t3 u32 [k][n]
            gemm_u<2, 4, 1, 1, 0, 3><<<4096, 256, 0, stream>>>(
                F, Op3 + (size_t)q * 8192, nullptr, P, 262144, 0);
            // G4: t3 u32 [k][n] (BFMT=0) x Ap4 -> t4' fp32 col-major [n][1024]
            gemm_u<8, 16, 0, 0, 0, 4><<<1024, 256, 0, stream>>>(
                P, Ap4 + (size_t)q * 131072, F, nullptr, 65536, 0);
            // G5: t4' [n][1024] (BFMT=2) x Sp5 -> env' [n][64] (A-slice c)
            gemm_u<32, 4, 1, 2, 1024, 5><<<256, 256, 0, stream>>>(
                F, Sp5 + (size_t)q * 131072, eout, nullptr, 16384, c * 16);
        }
    }

    // site 7: out = <env7 (col-major, in envB), w> with w built on the fly
    s7_c1<<<64, 256, 0, stream>>>(state, layer, SCR);
    s7_c2<<<256, 256, 0, stream>>>(SCR, oper, SCR + 16384);
    s7_c3<<<4096, 256, 0, stream>>>(SCR + 16384, layer, SCR + 81920);
    zero_out<<<1, 64, 0, stream>>>(out);
    s7_fused<<<1024, 256, 0, stream>>>(envB, SCR + 81920, sv, out);
}

// Round 8
// 2764.035 us; speedup vs baseline: 4.5056x; 1.2460x over previous
//
#include <hip/hip_runtime.h>

// ---------------------------------------------------------------------------
// <psi|U^dag O U|psi>, NQ=8, r=64 d=16 rl=16 ro=4.
// R8: (a) env back to row-major [a][n] (R7's col-major made s0_env a 64KB-
//     stride gather, 165us); G1 consumes it BFMT=1; s0_env/s7_fused are the
//     proven dense/broadcast versions.
//     (b) G4+G5 fused (gemm_g45): a G4 block's n-strip (O2,L,a4 fixed, b=64)
//     plus its m=(s,M2) range contains the FULL G5 contraction k5=(s,b) for
//     that (L,O2,a4). Phase A = G4 -> LDS t4L[(s,b)][M2] (split2 u32, pad 17);
//     phase B = small MFMA (wave = B' quarter; B-frag = Sp5 pack) writing the
//     env' row-chunk dense. Deletes t4's 67MB HBM round trip + G5 dispatch.
// Formats:
//   env  fp32 [a·64][n=(l,o,m2,b)·65536]
//   t1   u32  [k=(l,i)·256][n=(o,m2,a4,b)·65536]  (bf16 hi|lo<<16)
//   t2   fp32 [k=(o,j)·64][n=(L,m2,a4,b)·262144]
//   t3   u32  [k=(m2,k2)·256][n=(O2,L,a4,b)·65536]
// ---------------------------------------------------------------------------

typedef __attribute__((ext_vector_type(8))) short bf16x8;
typedef __attribute__((ext_vector_type(4))) float f32x4;
typedef __attribute__((ext_vector_type(4))) unsigned short us4;

static __device__ __forceinline__ unsigned short f2bf(float x) {
    union { float f; unsigned u; } a; a.f = x;
    return (unsigned short)((a.u + 0x7FFF + ((a.u >> 16) & 1)) >> 16);
}
static __device__ __forceinline__ float bf2f(unsigned short h) {
    union { unsigned u; float f; } a; a.u = (unsigned)h << 16; return a.f;
}
static __device__ __forceinline__ unsigned split2(float x) {
    unsigned short h = f2bf(x);
    unsigned short l = f2bf(x - bf2f(h));
    return (unsigned)h | ((unsigned)l << 16);
}

__global__ void write_diag_kernel(float* out, float v) {
    if (threadIdx.x == 0 && blockIdx.x == 0) out[0] = v;
}
__global__ void zero_out(float* o) {
    if (threadIdx.x == 0 && blockIdx.x == 0) o[0] = 0.0f;
}

// ---- A-operand fragment packs -------------------------------------------
// Pack layout: [(k0*MT+mt)*2+hl][lane(64)][8]; frag k = k0*32+quad*8+j,
// m = mt*16 + (lane&15).

// G2 (Ud, k=(l,i), m=(j,L)) / G4 (U, k=(m2,k2), m=(s,M2)); MT=16, KT=8
__global__ void prep_apack(const float* __restrict__ layer,
                           unsigned short* __restrict__ Ap2,
                           unsigned short* __restrict__ Ap4) {
    int idx = blockIdx.x * 256 + threadIdx.x;   // 65536
    int q = idx >> 13, k0 = (idx >> 10) & 7, mt = (idx >> 6) & 15, lane = idx & 63;
    int quad = lane >> 4, r = lane & 15;
    unsigned short h2[8], l2[8], h4[8], l4[8];
#pragma unroll
    for (int j = 0; j < 8; j++) {
        int k = k0 * 32 + quad * 8 + j;
        int m = mt * 16 + r;
        float v2 = layer[(size_t)q * 65536 +
                         (size_t)((((k >> 4) * 16 + (m >> 4)) * 16 + (k & 15)) * 16 + (m & 15))];
        float v4 = layer[(size_t)q * 65536 +
                         (size_t)((((k >> 4) * 16 + (k & 15)) * 16 + (m >> 4)) * 16 + (m & 15))];
        h2[j] = f2bf(v2); l2[j] = f2bf(v2 - bf2f(h2[j]));
        h4[j] = f2bf(v4); l4[j] = f2bf(v4 - bf2f(h4[j]));
    }
    size_t base = ((size_t)((q * 8 + k0) * 16 + mt) * 2) * 512 + lane * 8;
    *(us4*)(Ap2 + base)       = *(us4*)&h2[0];
    *(us4*)(Ap2 + base + 4)   = *(us4*)&h2[4];
    *(us4*)(Ap2 + base + 512) = *(us4*)&l2[0];
    *(us4*)(Ap2 + base + 516) = *(us4*)&l2[4];
    *(us4*)(Ap4 + base)       = *(us4*)&h4[0];
    *(us4*)(Ap4 + base + 4)   = *(us4*)&h4[4];
    *(us4*)(Ap4 + base + 512) = *(us4*)&l4[0];
    *(us4*)(Ap4 + base + 516) = *(us4*)&l4[4];
}

// G1 (S as A): Amat[k=a][m=(i,a4)] = state[q][a][i][c*16+a4]; MT=16, KT=2
__global__ void prep_spack1(const float* __restrict__ state,
                            unsigned short* __restrict__ Sp1) {
    int idx = blockIdx.x * 256 + threadIdx.x;   // 65536
    int q = idx >> 13, c = (idx >> 11) & 3, k0 = (idx >> 10) & 1,
        mt = (idx >> 6) & 15, lane = idx & 63;
    int quad = lane >> 4, lr = lane & 15;
    unsigned short h[8], l[8];
#pragma unroll
    for (int j = 0; j < 8; j++) {
        int k = k0 * 32 + quad * 8 + j;
        float v = state[(size_t)q * 65536 + (size_t)(k * 16 + mt) * 64 + c * 16 + lr];
        h[j] = f2bf(v); l[j] = f2bf(v - bf2f(h[j]));
    }
    size_t base = (size_t)(q * 4 + c) * 32768 + ((size_t)(k0 * 16 + mt) * 2) * 512 + lane * 8;
    *(us4*)(Sp1 + base)       = *(us4*)&h[0];
    *(us4*)(Sp1 + base + 4)   = *(us4*)&h[4];
    *(us4*)(Sp1 + base + 512) = *(us4*)&l[0];
    *(us4*)(Sp1 + base + 516) = *(us4*)&l[4];
}

// G5 (S): frag[k=(s,b)=s*64+b][col=B'] = state[q][b][s][B']; MT=4, KT=32
// (identical [16 x 32] lane layout serves as MFMA B-operand in gemm_g45)
__global__ void prep_spack5(const float* __restrict__ state,
                            unsigned short* __restrict__ Sp5) {
    int idx = blockIdx.x * 256 + threadIdx.x;   // 65536
    int q = idx >> 13, k0 = (idx >> 8) & 31, mt = (idx >> 6) & 3, lane = idx & 63;
    int quad = lane >> 4, lr = lane & 15;
    unsigned short h[8], l[8];
#pragma unroll
    for (int j = 0; j < 8; j++) {
        int k = k0 * 32 + quad * 8 + j;   // k = s*64+b
        int s = k >> 6, b = k & 63;
        float v = state[(size_t)q * 65536 + (size_t)(b * 16 + s) * 64 + mt * 16 + lr];
        h[j] = f2bf(v); l[j] = f2bf(v - bf2f(h[j]));
    }
    size_t base = (size_t)q * 131072 + ((size_t)(k0 * 4 + mt) * 2) * 512 + lane * 8;
    *(us4*)(Sp5 + base)       = *(us4*)&h[0];
    *(us4*)(Sp5 + base + 4)   = *(us4*)&h[4];
    *(us4*)(Sp5 + base + 512) = *(us4*)&l[0];
    *(us4*)(Sp5 + base + 516) = *(us4*)&l[4];
}

// G3 (O as A): Amat[k=(o,j2)][m=(k2,O2)] = oper[q][o][j2][k2][O2]; MT=4, KT=2
__global__ void prep_opack3(const float* __restrict__ oper,
                            unsigned short* __restrict__ Op3) {
    int idx = blockIdx.x * 256 + threadIdx.x;   // 4096
    int q = idx >> 9, k0 = (idx >> 8) & 1, mt = (idx >> 6) & 3, lane = idx & 63;
    int quad = lane >> 4, lr = lane & 15;
    unsigned short h[8], l[8];
#pragma unroll
    for (int j = 0; j < 8; j++) {
        int k = k0 * 32 + quad * 8 + j;
        int m = mt * 16 + lr;
        float v = oper[(size_t)q * 4096 + (size_t)(k * 16 + (m >> 2)) * 4 + (m & 3)];
        h[j] = f2bf(v); l[j] = f2bf(v - bf2f(h[j]));
    }
    size_t base = (size_t)q * 8192 + ((size_t)(k0 * 4 + mt) * 2) * 512 + lane * 8;
    *(us4*)(Op3 + base)       = *(us4*)&h[0];
    *(us4*)(Op3 + base + 4)   = *(us4*)&h[4];
    *(us4*)(Op3 + base + 512) = *(us4*)&l[0];
    *(us4*)(Op3 + base + 516) = *(us4*)&l[4];
}

// ---- site 0 (env0 = delta): env1 built by a cheap chain (fp32 exact) ----
__global__ void s0_g2(const float* __restrict__ state, const float* __restrict__ layer,
                      float* __restrict__ g2) {
    int t = blockIdx.x * 256 + threadIdx.x;          // 16384: [A][j][L]
    int A = t >> 8, j = (t >> 4) & 15, L = t & 15;
    float s = 0;
    for (int i = 0; i < 16; i++) s += state[i * 64 + A] * layer[(j * 16 + i) * 16 + L];
    g2[t] = s;
}
__global__ void s0_g3(const float* __restrict__ g2, const float* __restrict__ oper,
                      float* __restrict__ g3) {
    int t = blockIdx.x * 256 + threadIdx.x;          // 65536: [A][L][k][O]
    int A = t >> 10, L = (t >> 6) & 15, k = (t >> 2) & 15, O = t & 3;
    float s = 0;
    for (int j = 0; j < 16; j++) s += g2[A * 256 + j * 16 + L] * oper[(j * 16 + k) * 4 + O];
    g3[t] = s;
}
__global__ void s0_g4(const float* __restrict__ g3, const float* __restrict__ layer,
                      float* __restrict__ g4) {
    int t = blockIdx.x * 256 + threadIdx.x;          // 1048576: [A][L][O][s][M]
    int A = t >> 14, L = (t >> 10) & 15, O = (t >> 8) & 3, sp = (t >> 4) & 15, M = t & 15;
    float s = 0;
    for (int k = 0; k < 16; k++)
        s += g3[A * 1024 + L * 64 + k * 4 + O] * layer[(k * 16 + sp) * 16 + M];
    g4[t] = s;
}
// env row-major [A][L,O,M,B]: A block-uniform -> broadcast g4 reads, dense writes
__global__ void s0_env(const float* __restrict__ g4, const float* __restrict__ state,
                       float* __restrict__ env) {
    int t = blockIdx.x * 256 + threadIdx.x;          // 4194304: [A][L][O][M][B]
    int A = t >> 16, L = (t >> 12) & 15, O = (t >> 10) & 3, M = (t >> 6) & 15, B = t & 63;
    float s = 0;
    for (int sp = 0; sp < 16; sp++)
        s += g4[A * 16384 + L * 1024 + O * 256 + sp * 16 + M] * state[sp * 64 + B];
    env[t] = s;
}

// ---- site 7 chain (fp32) + fused dot ------------------------------------
__global__ void s7_c1(const float* __restrict__ state, const float* __restrict__ layer,
                      float* __restrict__ c1) {
    int t = blockIdx.x * 256 + threadIdx.x;          // 16384: [l][a][j]
    int l = t >> 10, a = (t >> 4) & 63, j = t & 15;
    float s = 0;
    for (int i = 0; i < 16; i++)
        s += state[7 * 65536 + (a * 16 + i) * 64] * layer[7 * 65536 + ((l * 16 + j) * 16 + i) * 16];
    c1[t] = s;
}
__global__ void s7_c2(const float* __restrict__ c1, const float* __restrict__ oper,
                      float* __restrict__ c2) {
    int t = blockIdx.x * 256 + threadIdx.x;          // 65536: [o][l][a][k]
    int o = t >> 14, l = (t >> 10) & 15, a = (t >> 4) & 63, k = t & 15;
    float s = 0;
    for (int j = 0; j < 16; j++)
        s += c1[l * 1024 + a * 16 + j] * oper[7 * 4096 + ((o * 16 + j) * 16 + k) * 4];
    c2[t] = s;
}
__global__ void s7_c3(const float* __restrict__ c2, const float* __restrict__ layer,
                      float* __restrict__ c3) {
    int t = blockIdx.x * 256 + threadIdx.x;          // 1048576: [m][o][l][a][s]
    int m = t >> 16, o = (t >> 14) & 3, l = (t >> 10) & 15, a = (t >> 4) & 63, sp = t & 15;
    float s = 0;
    for (int k = 0; k < 16; k++)
        s += c2[o * 16384 + l * 1024 + a * 16 + k] *
             layer[7 * 65536 + ((m * 16 + k) * 16 + sp) * 16];
    c3[t] = s;
}
__global__ void prep_sv(const float* __restrict__ state, float* __restrict__ sv) {
    int t = blockIdx.x * 256 + threadIdx.x;          // 1024: [b][sp]
    sv[t] = state[7 * 65536 + t * 64];
}
__global__ __launch_bounds__(256) void s7_fused(const float* __restrict__ env,
                                                const float* __restrict__ c3,
                                                const float* __restrict__ sv,
                                                float* __restrict__ out) {
    __shared__ float c3s[1024], svs[1024], red[256];
    int t = threadIdx.x;
    int n0 = blockIdx.x * 64;            // 1024 blocks; n=(l,o,m,b)
    int l = n0 >> 12, o = (n0 >> 10) & 3, m = (n0 >> 6) & 15;
    const float* c3b = c3 + m * 65536 + o * 16384 + l * 1024;   // [a][sp]
    for (int i = t; i < 1024; i += 256) { c3s[i] = c3b[i]; svs[i] = sv[i]; }
    __syncthreads();
    float s = 0;
    int b = t & 63, ag = t >> 6;
#pragma unroll
    for (int g = 0; g < 16; g++) {
        int a = ag * 16 + g;
        float e = env[(size_t)a * 65536 + n0 + b];   // row-major
        float w = 0;
#pragma unroll
        for (int sp = 0; sp < 16; sp++) w += c3s[a * 16 + sp] * svs[b * 16 + sp];
        s += e * w;
    }
    red[t] = s; __syncthreads();
    for (int off = 128; off; off >>= 1) { if (t < off) red[t] += red[t + off]; __syncthreads(); }
    if (t == 0) atomicAdd(out, red[0]);
}

// ---- unified bf16x3 MFMA GEMM (G1 / G2 / G3) -----------------------------
// C[m,n] = sum_k Amat[k,m]*B[k,n]. Block = 4 waves, BN=64.
// WS=0: waves split m (M=256, MT=16); WS=1: waves split n (M=64, MT=4).
// BFMT=0: B u32 split-pair [k][n]; BFMT=1: B fp32 [k][n] (split on stage).
template <int KT, int MT, int WS, int BFMT, int SM>
__global__ __launch_bounds__(256) void gemm_u(const void* __restrict__ Bv,
                                              const unsigned short* __restrict__ Ap,
                                              float* __restrict__ Cf,
                                              unsigned* __restrict__ Cu,
                                              int Nfull) {
    constexpr int NT = (WS == 0) ? 4 : 1;
    __shared__ unsigned short Bs_h[64 * 40];
    __shared__ unsigned short Bs_l[64 * 40];
    const int tid = threadIdx.x, lane = tid & 63, wave = tid >> 6;
    const int quad = lane >> 4, lr = lane & 15;
    const int n0 = blockIdx.x * 64;
    const int snn = tid & 63, skg = tid >> 6;

    f32x4 acc[4][NT];
#pragma unroll
    for (int i = 0; i < 4; i++)
#pragma unroll
        for (int j = 0; j < NT; j++)
#pragma unroll
            for (int r = 0; r < 4; r++) acc[i][j][r] = 0.0f;

    unsigned ub[2][4];
    float    fb[2][4];

    auto load_tile = [&](int k0) {
        if constexpr (BFMT == 0) {
            const unsigned* Bp = (const unsigned*)Bv;
#pragma unroll
            for (int v = 0; v < 2; v++)
#pragma unroll
                for (int i = 0; i < 4; i++) {
                    int kk = (v * 4 + skg) * 4 + i;
                    ub[v][i] = Bp[(size_t)(k0 * 32 + kk) * Nfull + n0 + snn];
                }
        } else {
            const float* Bf = (const float*)Bv;
#pragma unroll
            for (int v = 0; v < 2; v++)
#pragma unroll
                for (int i = 0; i < 4; i++) {
                    int kk = (v * 4 + skg) * 4 + i;
                    fb[v][i] = Bf[(size_t)(k0 * 32 + kk) * Nfull + n0 + snn];
                }
        }
    };
    auto store_tile = [&]() {
#pragma unroll
        for (int v = 0; v < 2; v++) {
            us4 hv, lv;
#pragma unroll
            for (int i = 0; i < 4; i++) {
                unsigned s;
                if constexpr (BFMT == 0) s = ub[v][i];
                else                     s = split2(fb[v][i]);
                hv[i] = (unsigned short)s;
                lv[i] = (unsigned short)(s >> 16);
            }
            int base = snn * 40 + (v * 4 + skg) * 4;
            *(us4*)(&Bs_h[base]) = hv;
            *(us4*)(&Bs_l[base]) = lv;
        }
    };

    load_tile(0);
    store_tile();
    for (int k0 = 0; k0 < KT; k0++) {
        __syncthreads();
        if (k0 + 1 < KT) load_tile(k0 + 1);
        bf16x8 ah[4], al[4];
#pragma unroll
        for (int mt = 0; mt < 4; mt++) {
            int gmt = (WS == 0) ? (wave * 4 + mt) : mt;
            const unsigned short* ap = Ap + ((size_t)(k0 * MT + gmt) * 2) * 512 + lane * 8;
            ah[mt] = *(const bf16x8*)ap;
            al[mt] = *(const bf16x8*)(ap + 512);
        }
#pragma unroll
        for (int nt = 0; nt < NT; nt++) {
            int nl = (WS == 0) ? (nt * 16 + lr) : (wave * 16 + lr);
            bf16x8 bh = *(bf16x8*)(&Bs_h[nl * 40 + quad * 8]);
            bf16x8 bl = *(bf16x8*)(&Bs_l[nl * 40 + quad * 8]);
#pragma unroll
            for (int mt = 0; mt < 4; mt++) {
                acc[mt][nt] = __builtin_amdgcn_mfma_f32_16x16x32_bf16(ah[mt], bh, acc[mt][nt], 0, 0, 0);
                acc[mt][nt] = __builtin_amdgcn_mfma_f32_16x16x32_bf16(ah[mt], bl, acc[mt][nt], 0, 0, 0);
                acc[mt][nt] = __builtin_amdgcn_mfma_f32_16x16x32_bf16(al[mt], bh, acc[mt][nt], 0, 0, 0);
            }
        }
        __syncthreads();
        if (k0 + 1 < KT) store_tile();
    }

#pragma unroll
    for (int mt = 0; mt < 4; mt++) {
        int gmt = (WS == 0) ? (wave * 4 + mt) : mt;
#pragma unroll
        for (int nt = 0; nt < NT; nt++) {
            int n = n0 + ((WS == 0) ? nt * 16 : wave * 16) + lr;
#pragma unroll
            for (int r = 0; r < 4; r++) {
                int m = gmt * 16 + quad * 4 + r;
                float val = acc[mt][nt][r];
                if constexpr (SM == 1) {
                    // n = env col (l,o,m2,b); m=(i,a4) -> t1[(l,i)][o,m2,a4,b]
                    int l = n >> 12, o = (n >> 10) & 3, m2 = (n >> 6) & 15, b = n & 63;
                    Cu[(size_t)(l * 16 + (m >> 4)) * 65536 +
                       o * 16384 + m2 * 1024 + (m & 15) * 64 + b] = split2(val);
                } else if constexpr (SM == 2) {
                    // n = t1 col (o,m2,a4,b); m=(j,L) -> t2[(o,j)][L,m2,a4,b]
                    Cf[(size_t)((n >> 14) * 16 + (m >> 4)) * 262144 +
                       (m & 15) * 16384 + (n & 16383)] = val;
                } else {
                    // SM == 3: n = t2 col (L,m2,a4,b); m=(k2,O2)
                    //  -> t3[(m2,k2)][O2,L,a4,b]
                    int L = n >> 14, m2 = (n >> 10) & 15;
                    Cu[(size_t)(m2 * 16 + (m >> 2)) * 65536 +
                       (m & 3) * 16384 + L * 1024 + (n & 1023)] = split2(val);
                }
            }
        }
    }
}

// ---- fused G4+G5 ---------------------------------------------------------
// Phase A: G4 on the block's t3 n-strip (O2,L,a4 fixed, b=0..63), m=(s,M2).
//   Epilogue -> LDS t4L[(s*64+b)][M2] as split2 u32, row pad 17.
// Phase B: env'[A0+a4][L,O2,M2,B'] += sum_{s,b} t4 * S. Wave w = B' quarter.
//   A-frag = t4L (m=M2=lane&15), B-frag = Sp5 pack (n=B').
__global__ __launch_bounds__(256) void gemm_g45(const unsigned* __restrict__ Bp,
                                                const unsigned short* __restrict__ Ap4,
                                                const unsigned short* __restrict__ Sp5,
                                                float* __restrict__ env, int A0) {
    __shared__ unsigned short Bs_h[64 * 40];
    __shared__ unsigned short Bs_l[64 * 40];
    __shared__ unsigned t4L[1024 * 17];
    const int tid = threadIdx.x, lane = tid & 63, wave = tid >> 6;
    const int quad = lane >> 4, lr = lane & 15;
    const int n0 = blockIdx.x * 64;
    const int O2 = n0 >> 14, L = (n0 >> 10) & 15, a4 = (n0 >> 6) & 15;
    const int snn = tid & 63, skg = tid >> 6;

    f32x4 acc[4][4];
#pragma unroll
    for (int i = 0; i < 4; i++)
#pragma unroll
        for (int j = 0; j < 4; j++)
#pragma unroll
            for (int r = 0; r < 4; r++) acc[i][j][r] = 0.0f;

    unsigned ub[2][4];
    auto load_tile = [&](int k0) {
#pragma unroll
        for (int v = 0; v < 2; v++)
#pragma unroll
            for (int i = 0; i < 4; i++) {
                int kk = (v * 4 + skg) * 4 + i;
                ub[v][i] = Bp[(size_t)(k0 * 32 + kk) * 65536 + n0 + snn];
            }
    };
    auto store_tile = [&]() {
#pragma unroll
        for (int v = 0; v < 2; v++) {
            us4 hv, lv;
#pragma unroll
            for (int i = 0; i < 4; i++) {
                hv[i] = (unsigned short)ub[v][i];
                lv[i] = (unsigned short)(ub[v][i] >> 16);
            }
            int base = snn * 40 + (v * 4 + skg) * 4;
            *(us4*)(&Bs_h[base]) = hv;
            *(us4*)(&Bs_l[base]) = lv;
        }
    };

    load_tile(0);
    store_tile();
    for (int k0 = 0; k0 < 8; k0++) {
        __syncthreads();
        if (k0 + 1 < 8) load_tile(k0 + 1);
        bf16x8 ah[4], al[4];
#pragma unroll
        for (int mt = 0; mt < 4; mt++) {
            const unsigned short* ap =
                Ap4 + ((size_t)(k0 * 16 + wave * 4 + mt) * 2) * 512 + lane * 8;
            ah[mt] = *(const bf16x8*)ap;
            al[mt] = *(const bf16x8*)(ap + 512);
        }
#pragma unroll
        for (int nt = 0; nt < 4; nt++) {
            int nl = nt * 16 + lr;
            bf16x8 bh = *(bf16x8*)(&Bs_h[nl * 40 + quad * 8]);
            bf16x8 bl = *(bf16x8*)(&Bs_l[nl * 40 + quad * 8]);
#pragma unroll
            for (int mt = 0; mt < 4; mt++) {
                acc[mt][nt] = __builtin_amdgcn_mfma_f32_16x16x32_bf16(ah[mt], bh, acc[mt][nt], 0, 0, 0);
                acc[mt][nt] = __builtin_amdgcn_mfma_f32_16x16x32_bf16(ah[mt], bl, acc[mt][nt], 0, 0, 0);
                acc[mt][nt] = __builtin_amdgcn_mfma_f32_16x16x32_bf16(al[mt], bh, acc[mt][nt], 0, 0, 0);
            }
        }
        __syncthreads();
        if (k0 + 1 < 8) store_tile();
    }

    // phase A epilogue -> LDS t4L[(s*64+b)*17 + M2] = split2(t4)
#pragma unroll
    for (int mt = 0; mt < 4; mt++) {
        int s = wave * 4 + mt;
#pragma unroll
        for (int nt = 0; nt < 4; nt++) {
            int b = nt * 16 + lr;
#pragma unroll
            for (int r = 0; r < 4; r++)
                t4L[(s * 64 + b) * 17 + quad * 4 + r] = split2(acc[mt][nt][r]);
        }
    }
    __syncthreads();

    // phase B: K=1024 over (s,b); wave = B' quarter; one 16x16 acc.
    f32x4 acc5;
#pragma unroll
    for (int r = 0; r < 4; r++) acc5[r] = 0.0f;
    for (int k0 = 0; k0 < 32; k0++) {
        bf16x8 th, tl;
#pragma unroll
        for (int j = 0; j < 8; j++) {
            unsigned u = t4L[(k0 * 32 + quad * 8 + j) * 17 + lr];
            th[j] = (short)(u & 0xffff);
            tl[j] = (short)(u >> 16);
        }
        const unsigned short* bp = Sp5 + ((size_t)(k0 * 4 + wave) * 2) * 512 + lane * 8;
        bf16x8 sh = *(const bf16x8*)bp;
        bf16x8 sl = *(const bf16x8*)(bp + 512);
        acc5 = __builtin_amdgcn_mfma_f32_16x16x32_bf16(th, sh, acc5, 0, 0, 0);
        acc5 = __builtin_amdgcn_mfma_f32_16x16x32_bf16(th, sl, acc5, 0, 0, 0);
        acc5 = __builtin_amdgcn_mfma_f32_16x16x32_bf16(tl, sh, acc5, 0, 0, 0);
    }
    // C[row=M2=quad*4+r][col=B'=wave*16+lr] -> env[A0+a4][L,O2,M2,B'] dense
    float* dst = env + (size_t)(A0 + a4) * 65536 + L * 4096 + O2 * 1024 + wave * 16 + lr;
#pragma unroll
    for (int r = 0; r < 4; r++) dst[(quad * 4 + r) * 64] = acc5[r];
}

extern "C" void kernel_launch(void* const* d_in, const int* in_sizes, int n_in,
                              void* d_out, int out_size, void* d_ws, size_t ws_size,
                              hipStream_t stream) {
    const float* state = (const float*)d_in[0];   // [8,64,16,64]
    const float* layer = (const float*)d_in[1];   // [1,8,16,16,16,16]
    const float* oper  = (const float*)d_in[2];   // [8,4,16,16,4]
    float* out = (float*)d_out;

    // ws: F(16.8M f32) | P(16.8M u32) | envA | envB | Ap2|Ap4|Sp1|Sp5|Op3 | sv
    const size_t need = (16777216ull + 16777216ull + 2 * 4194304ull) * 4ull +
                        (4 * 1048576ull + 65536ull) * 2ull + 4096ull;
    if (ws_size < need) {
        write_diag_kernel<<<1, 64, 0, stream>>>(out, (float)ws_size);
        return;
    }
    float* F    = (float*)d_ws;
    unsigned* P = (unsigned*)(F + 16777216);
    float* envA = (float*)(P + 16777216);
    float* envB = envA + 4194304;
    unsigned short* Ap2 = (unsigned short*)(envB + 4194304);
    unsigned short* Ap4 = Ap2 + 1048576;
    unsigned short* Sp1 = Ap4 + 1048576;
    unsigned short* Sp5 = Sp1 + 1048576;
    unsigned short* Op3 = Sp5 + 1048576;
    float* sv = (float*)(Op3 + 65536);
    float* SCR = F;   // boundary-chain fp32 scratch (F free at those times)

    prep_apack<<<256, 256, 0, stream>>>(layer, Ap2, Ap4);
    prep_spack1<<<256, 256, 0, stream>>>(state, Sp1);
    prep_spack5<<<256, 256, 0, stream>>>(state, Sp5);
    prep_opack3<<<16, 256, 0, stream>>>(oper, Op3);
    prep_sv<<<4, 256, 0, stream>>>(state, sv);

    // site 0 -> envB (exact fp32), env row-major [a][n]
    s0_g2<<<64, 256, 0, stream>>>(state, layer, SCR);
    s0_g3<<<256, 256, 0, stream>>>(SCR, oper, SCR + 16384);
    s0_g4<<<4096, 256, 0, stream>>>(SCR + 16384, layer, SCR + 81920);
    s0_env<<<16384, 256, 0, stream>>>(SCR + 81920, state, envB);

    for (int q = 1; q < 7; q++) {
        float* ein  = (q & 1) ? envB : envA;
        float* eout = (q & 1) ? envA : envB;
        for (int c = 0; c < 4; c++) {
            // G1: env fp32 [a][n] (BFMT=1) x Sp1 -> t1 u32 [k][n]
            gemm_u<2, 16, 0, 1, 1><<<1024, 256, 0, stream>>>(
                ein, Sp1 + (size_t)(q * 4 + c) * 32768, nullptr, P, 65536);
            // G2: t1 u32 [k][n] (BFMT=0) x Ap2 -> t2 fp32 [k][n]
            gemm_u<8, 16, 0, 0, 2><<<1024, 256, 0, stream>>>(
                P, Ap2 + (size_t)q * 131072, F, nullptr, 65536);
            // G3: t2 fp32 [k][n] (BFMT=1) x Op3 -> t3 u32 [k][n]
            gemm_u<2, 4, 1, 1, 3><<<4096, 256, 0, stream>>>(
                F, Op3 + (size_t)q * 8192, nullptr, P, 262144);
            // G4+G5 fused: t3 u32 [k][n] x Ap4 -> (LDS t4) x Sp5 -> env' slice
            gemm_g45<<<1024, 256, 0, stream>>>(
                P, Ap4 + (size_t)q * 131072, Sp5 + (size_t)q * 131072, eout, c * 16);
        }
    }

    // site 7: out = <env7 (row-major, in envB), w> with w built on the fly
    s7_c1<<<64, 256, 0, stream>>>(state, layer, SCR);
    s7_c2<<<256, 256, 0, stream>>>(SCR, oper, SCR + 16384);
    s7_c3<<<4096, 256, 0, stream>>>(SCR + 16384, layer, SCR + 81920);
    zero_out<<<1, 64, 0, stream>>>(out);
    s7_fused<<<1024, 256, 0, stream>>>(envB, SCR + 81920, sv, out);
}